// Round 14
// baseline (423.410 us; speedup 1.0000x reference)
//
#include <hip/hip_runtime.h>

using short8 = __attribute__((ext_vector_type(8))) short;
using f32x4  = __attribute__((ext_vector_type(4))) float;
typedef unsigned short u16;
typedef unsigned int u32;

__device__ __forceinline__ float b2f(u16 u){
    return __uint_as_float(((u32)u) << 16);
}
__device__ __forceinline__ u16 f2b(float f){
    u32 x = __float_as_uint(f);
    u32 r = (x + 0x7FFFu + ((x >> 16) & 1u)) >> 16;
    return (u16)r;
}
__device__ __forceinline__ float ldx(const void* p, size_t i, bool f32){
    return f32 ? ((const float*)p)[i] : b2f(((const u16*)p)[i]);
}
__device__ __forceinline__ float sigf(float x){
    return __builtin_amdgcn_rcpf(1.0f + __expf(-x));
}
__device__ __forceinline__ float tanhf_(float x){
    float e = __expf(2.0f*x);
    return 1.0f - 2.0f*__builtin_amdgcn_rcpf(e + 1.0f);
}
__device__ __forceinline__ u32 cvtpk(float lo, float hi){
    u32 r;
    asm("v_cvt_pk_bf16_f32 %0, %1, %2" : "=v"(r) : "v"(lo), "v"(hi));
    return r;
}

#define GLDS(g, l) __builtin_amdgcn_global_load_lds((const __attribute__((address_space(1))) void*)(g), \
                        (__attribute__((address_space(3))) void*)(l), 16, 0, 0)

// ---------------- dtype probe ----------------
__global__ void probe_dtype(const void* w, int* flag){
    const u16* up = (const u16*)w;
    int lane = threadIdx.x & 63;
    int cnt = 0;
    for (int i = lane; i < 256; i += 64){
        u16 u = up[2*i];
        int e = (u >> 7) & 0xFF;
        if (e >= 100 && e <= 126) cnt++;
    }
    #pragma unroll
    for (int off = 32; off; off >>= 1) cnt += __shfl_xor(cnt, off);
    if (lane == 0) *flag = (cnt >= 192) ? 0 : 1;   // 1 == inputs are f32
}

// ---------------- multi transpose (K,N)->(Npad,K), up to 8 weights per launch ----------------
struct TP { const void* src[8]; u16* dst[8]; };
__global__ __launch_bounds__(256) void transpose_multi(TP tp, int K, int N, int Npad,
                                                       const int* __restrict__ dflag){
    __shared__ u16 tile[32][33];
    bool f32 = (*dflag != 0);
    const void* in = tp.src[blockIdx.z];
    u16* out = tp.dst[blockIdx.z];
    int bx = blockIdx.x, by = blockIdx.y;
    int tx = threadIdx.x, ty = threadIdx.y;   // (32,8)
    int n = bx*32 + tx;
    #pragma unroll
    for (int i = 0; i < 32; i += 8){
        int k = by*32 + ty + i;
        u16 v = 0;
        if (n < N && k < K)
            v = f32 ? f2b(((const float*)in)[(size_t)k*N + n]) : ((const u16*)in)[(size_t)k*N + n];
        tile[ty+i][tx] = v;
    }
    __syncthreads();
    int k2 = by*32 + tx;
    #pragma unroll
    for (int i = 0; i < 32; i += 8){
        int n2 = bx*32 + ty + i;
        if (n2 < Npad && k2 < K) out[(size_t)n2*K + k2] = tile[tx][ty+i];
    }
}

// ---------------- embedding gather + relu -> bf16 ----------------
__global__ __launch_bounds__(256) void gather_emb(const int* __restrict__ seq, const void* __restrict__ embed,
                                                  u16* __restrict__ x_emb, const int* __restrict__ dflag){
    bool f32 = (*dflag != 0);
    int idx = blockIdx.x*256 + threadIdx.x;
    if (idx >= 1280*512) return;
    int row = idx >> 9, r = idx & 511;
    int b = row / 20, t = row % 20;
    int w = seq[b*21 + t];
    float v = ldx(embed, (size_t)w*512 + r, f32);
    x_emb[idx] = f2b(fmaxf(v, 0.f));
}

// ---------------- mean over A of af -> bf16 ----------------
__global__ __launch_bounds__(256) void mean_af_kernel(const u16* __restrict__ af, u16* __restrict__ mean_af){
    int b = blockIdx.x, tid = threadIdx.x;
    for (int r = tid; r < 512; r += 256){
        float s = 0.f;
        for (int a = 0; a < 196; ++a) s += b2f(af[((size_t)(b*196+a))*512 + r]);
        mean_af[b*512+r] = f2b(s * (1.0f/196.0f));
    }
}

// ---------------- af GEMM, TM=128: A external (f32 reg-staged cvtpk / bf16 GLDS), BT bf16 ----------------
// Produces the SAME LDS image as the GLDS-bf16 path (linear dest chunk c, source slot (c&7)^(row&7)),
// so the conflict-free read side is identical. C = relu(A@B + bias) -> bf16.
__global__ __launch_bounds__(256) void gemm_aff(const void* __restrict__ A, const u16* __restrict__ BT,
                                                int N, int K, const void* __restrict__ bias1,
                                                u16* __restrict__ Cb, int Nvalid, int Mvalid,
                                                const int* __restrict__ dflag){
    __shared__ u16 As[128*64];
    __shared__ u16 Bs[64*64];
    bool f32 = (*dflag != 0);
    int tid = threadIdx.x, lane = tid & 63, w = tid >> 6;
    int lr = lane & 15, kq = lane >> 4;

    int gN = gridDim.x;
    int nwg = gN * gridDim.y;
    int flat = blockIdx.y*gN + blockIdx.x;
    int q = nwg >> 3, r = nwg & 7;
    int xcd = flat & 7, pos = flat >> 3;
    int wgid = (xcd < r ? xcd*(q+1) : r*(q+1) + (xcd-r)*q) + pos;
    int bm = wgid / gN, bn = wgid % gN;
    int row0 = bm*128, col0 = bn*64;

    f32x4 acc[2][4];
    #pragma unroll
    for (int m=0;m<2;++m)
        #pragma unroll
        for (int n=0;n<4;++n) acc[m][n] = (f32x4){0.f,0.f,0.f,0.f};

    for (int k0 = 0; k0 < K; k0 += 64){
        if (f32){
            const float* Af = (const float*)A;
            #pragma unroll
            for (int i=0;i<4;++i){
                int c = i*256 + tid;
                int row = c>>3;
                int sg = (c&7) ^ (row&7);
                const float* g = Af + (size_t)(row0+row)*K + k0 + sg*8;
                float4 lo = *(const float4*)g;
                float4 hi = *(const float4*)(g+4);
                u32 pk[4] = { cvtpk(lo.x,lo.y), cvtpk(lo.z,lo.w),
                              cvtpk(hi.x,hi.y), cvtpk(hi.z,hi.w) };
                *(uint4*)(As + (size_t)c*8) = *(const uint4*)pk;
            }
        } else {
            const u16* Ab = (const u16*)A;
            #pragma unroll
            for (int i=0;i<4;++i){
                int c = i*256 + tid;
                int row = c>>3, slot = (c&7) ^ (row&7);
                GLDS((const char*)(Ab + (size_t)(row0+row)*K + k0) + slot*16,
                     As + (size_t)(i*256 + w*64)*8);
            }
        }
        #pragma unroll
        for (int i=0;i<2;++i){
            int c = i*256 + tid;
            int row = c>>3, slot = (c&7) ^ (row&7);
            GLDS((const char*)BT + ((size_t)(col0+row)*K + k0)*2 + slot*16,
                 Bs + (size_t)(i*256 + w*64)*8);
        }
        __syncthreads();
        short8 av[2][2], bv[4][2];
        #pragma unroll
        for (int ks=0;ks<2;++ks){
            #pragma unroll
            for (int m=0;m<2;++m){
                int rrow = w*32 + m*16 + lr;
                int sl = (ks*4+kq) ^ (rrow&7);
                av[m][ks] = *(const short8*)(As + rrow*64 + sl*8);
            }
            #pragma unroll
            for (int n=0;n<4;++n){
                int rrow = n*16 + lr;
                int sl = (ks*4+kq) ^ (rrow&7);
                bv[n][ks] = *(const short8*)(Bs + rrow*64 + sl*8);
            }
        }
        #pragma unroll
        for (int ks=0;ks<2;++ks)
            #pragma unroll
            for (int m=0;m<2;++m)
                #pragma unroll
                for (int n=0;n<4;++n)
                    acc[m][n] = __builtin_amdgcn_mfma_f32_16x16x32_bf16(av[m][ks], bv[n][ks], acc[m][n], 0,0,0);
        __syncthreads();
    }

    #pragma unroll
    for (int n=0;n<4;++n){
        int col = col0 + n*16 + lr;
        float bvv = (col < Nvalid && bias1) ? ldx(bias1, col, f32) : 0.f;
        #pragma unroll
        for (int m=0;m<2;++m){
            #pragma unroll
            for (int rr=0;rr<4;++rr){
                int row = row0 + w*32 + m*16 + kq*4 + rr;
                if (row < Mvalid && col < Nvalid){
                    float v = fmaxf(acc[m][n][rr] + bvv, 0.f);
                    Cb[(size_t)row*N + col] = f2b(v);
                }
            }
        }
    }
}

// ---------------- MFMA GEMM: A(M,K) bf16, BT(Npad,K) bf16; tile TM x 64, BK=64 ----------------
// perm: if 1, C index remapped for wgb: row b*20+t -> t*64+b, col gate*512+r -> r*6+gate
template<int TM>
__global__ __launch_bounds__(256) void gemm_tn(const u16* __restrict__ A, const u16* __restrict__ BT,
                                               int N, int K,
                                               const void* __restrict__ bias1, const void* __restrict__ bias2,
                                               const float* __restrict__ rowAdd, int rowDiv,
                                               float* __restrict__ Cf, u16* __restrict__ Cb,
                                               int act, int Nvalid, int Mvalid,
                                               const int* __restrict__ dflag, int perm){
    constexpr int MW = TM/64;
    __shared__ u16 As[TM*64];
    __shared__ u16 Bs[64*64];
    bool f32 = (*dflag != 0);
    int tid = threadIdx.x, lane = tid & 63, w = tid >> 6;
    int lr = lane & 15, kq = lane >> 4;

    int gN = gridDim.x;
    int nwg = gN * gridDim.y;
    int flat = blockIdx.y*gN + blockIdx.x;
    int q = nwg >> 3, r = nwg & 7;
    int xcd = flat & 7, pos = flat >> 3;
    int wgid = (xcd < r ? xcd*(q+1) : r*(q+1) + (xcd-r)*q) + pos;
    int bm = wgid / gN, bn = wgid % gN;
    int row0 = bm*TM, col0 = bn*64;

    f32x4 acc[MW][4];
    #pragma unroll
    for (int m=0;m<MW;++m)
        #pragma unroll
        for (int n=0;n<4;++n) acc[m][n] = (f32x4){0.f,0.f,0.f,0.f};

    for (int k0 = 0; k0 < K; k0 += 64){
        #pragma unroll
        for (int i=0;i<TM/32;++i){
            int c = i*256 + tid;
            int row = c>>3, slot = (c&7) ^ (row&7);
            GLDS((const char*)A + ((size_t)(row0+row)*K + k0)*2 + slot*16,
                 As + (size_t)(i*256 + w*64)*8);
        }
        #pragma unroll
        for (int i=0;i<2;++i){
            int c = i*256 + tid;
            int row = c>>3, slot = (c&7) ^ (row&7);
            GLDS((const char*)BT + ((size_t)(col0+row)*K + k0)*2 + slot*16,
                 Bs + (size_t)(i*256 + w*64)*8);
        }
        __syncthreads();
        short8 av[MW][2], bv[4][2];
        #pragma unroll
        for (int ks=0;ks<2;++ks){
            #pragma unroll
            for (int m=0;m<MW;++m){
                int rrow = w*(TM/4) + m*16 + lr;
                int sl = (ks*4+kq) ^ (rrow&7);
                av[m][ks] = *(const short8*)(As + rrow*64 + sl*8);
            }
            #pragma unroll
            for (int n=0;n<4;++n){
                int rrow = n*16 + lr;
                int sl = (ks*4+kq) ^ (rrow&7);
                bv[n][ks] = *(const short8*)(Bs + rrow*64 + sl*8);
            }
        }
        #pragma unroll
        for (int ks=0;ks<2;++ks)
            #pragma unroll
            for (int m=0;m<MW;++m)
                #pragma unroll
                for (int n=0;n<4;++n)
                    acc[m][n] = __builtin_amdgcn_mfma_f32_16x16x32_bf16(av[m][ks], bv[n][ks], acc[m][n], 0,0,0);
        __syncthreads();
    }

    #pragma unroll
    for (int n=0;n<4;++n){
        int col = col0 + n*16 + lr;
        float bvv = 0.f;
        if (col < Nvalid){
            if (bias1) bvv += ldx(bias1, col, f32);
            if (bias2) bvv += ldx(bias2, col, f32);
        }
        #pragma unroll
        for (int m=0;m<MW;++m){
            #pragma unroll
            for (int rr=0;rr<4;++rr){
                int row = row0 + w*(TM/4) + m*16 + kq*4 + rr;
                if (row < Mvalid && col < Nvalid){
                    float v = acc[m][n][rr] + bvv;
                    if (rowAdd) v += rowAdd[(size_t)(row/rowDiv)*N + col];
                    if (act == 1) v = fmaxf(v, 0.f);
                    else if (act == 2) v = tanhf_(v);
                    size_t o;
                    if (perm){
                        int orow = (row % 20)*64 + row/20;
                        int ocol = (col & 511)*6 + (col >> 9);
                        o = (size_t)orow*N + ocol;
                    } else {
                        o = (size_t)row*N + col;
                    }
                    if (Cf) Cf[o] = v;
                    if (Cb) Cb[o] = f2b(v);
                }
            }
        }
    }
}

// ---------------- z-batched pair of 512x512 GEMMs (M=1280), TM=64 ----------------
struct GP { const u16* A; const u16* BT; const void* b1; float* Cf; u16* Cb; int act; };
struct GP2 { GP g[2]; };
__global__ __launch_bounds__(256) void gemm_tn2(GP2 ps, int N, int K, int Nvalid, int Mvalid,
                                                const int* __restrict__ dflag){
    __shared__ u16 As[64*64];
    __shared__ u16 Bs[64*64];
    bool f32 = (*dflag != 0);
    GP gp = ps.g[blockIdx.z];
    int tid = threadIdx.x, lane = tid & 63, w = tid >> 6;
    int lr = lane & 15, kq = lane >> 4;

    int gN = gridDim.x;
    int nwg = gN * gridDim.y;
    int flat = blockIdx.y*gN + blockIdx.x;
    int q = nwg >> 3, r = nwg & 7;
    int xcd = flat & 7, pos = flat >> 3;
    int wgid = (xcd < r ? xcd*(q+1) : r*(q+1) + (xcd-r)*q) + pos;
    int bm = wgid / gN, bn = wgid % gN;
    int row0 = bm*64, col0 = bn*64;

    f32x4 acc[4];
    #pragma unroll
    for (int n=0;n<4;++n) acc[n] = (f32x4){0.f,0.f,0.f,0.f};

    for (int k0 = 0; k0 < K; k0 += 64){
        {
            int c = tid;
            int row = c>>3, slot = (c&7) ^ (row&7);
            GLDS((const char*)gp.A + ((size_t)(row0+row)*K + k0)*2 + slot*16,
                 As + (size_t)(w*64)*8);
            c = 256 + tid;
            row = c>>3; slot = (c&7) ^ (row&7);
            GLDS((const char*)gp.A + ((size_t)(row0+row)*K + k0)*2 + slot*16,
                 As + (size_t)(256 + w*64)*8);
            c = tid;
            row = c>>3; slot = (c&7) ^ (row&7);
            GLDS((const char*)gp.BT + ((size_t)(col0+row)*K + k0)*2 + slot*16,
                 Bs + (size_t)(w*64)*8);
            c = 256 + tid;
            row = c>>3; slot = (c&7) ^ (row&7);
            GLDS((const char*)gp.BT + ((size_t)(col0+row)*K + k0)*2 + slot*16,
                 Bs + (size_t)(256 + w*64)*8);
        }
        __syncthreads();
        short8 av[2], bv[4][2];
        #pragma unroll
        for (int ks=0;ks<2;++ks){
            int rrow = w*16 + lr;
            int sl = (ks*4+kq) ^ (rrow&7);
            av[ks] = *(const short8*)(As + rrow*64 + sl*8);
            #pragma unroll
            for (int n=0;n<4;++n){
                int rr2 = n*16 + lr;
                int sl2 = (ks*4+kq) ^ (rr2&7);
                bv[n][ks] = *(const short8*)(Bs + rr2*64 + sl2*8);
            }
        }
        #pragma unroll
        for (int ks=0;ks<2;++ks)
            #pragma unroll
            for (int n=0;n<4;++n)
                acc[n] = __builtin_amdgcn_mfma_f32_16x16x32_bf16(av[ks], bv[n][ks], acc[n], 0,0,0);
        __syncthreads();
    }

    #pragma unroll
    for (int n=0;n<4;++n){
        int col = col0 + n*16 + lr;
        float bvv = (col < Nvalid && gp.b1) ? ldx(gp.b1, col, f32) : 0.f;
        #pragma unroll
        for (int rr=0;rr<4;++rr){
            int row = row0 + w*16 + kq*4 + rr;
            if (row < Mvalid && col < Nvalid){
                float v = acc[n][rr] + bvv;
                if (gp.act == 1) v = fmaxf(v, 0.f);
                else if (gp.act == 2) v = tanhf_(v);
                size_t o = (size_t)row*N + col;
                if (gp.Cf) gp.Cf[o] = v;
                if (gp.Cb) gp.Cb[o] = f2b(v);
            }
        }
    }
}

// ---------------- LSTM step v3: 256 blocks x 192 thr; wgb in [t][b][r][6] layout ----------------
#define GP3 52
__global__ __launch_bounds__(192) void lstm_step(const u16* __restrict__ h_in, const u16* __restrict__ WT_h,
                                                 const float* __restrict__ wgb, float* __restrict__ cstate,
                                                 u16* __restrict__ h_out, u16* __restrict__ sent_all,
                                                 u16* __restrict__ hy_all, int t){
    __shared__ float gates[16*GP3];
    int tid = threadIdx.x, lane = tid & 63, w = tid >> 6;   // w in 0..2
    int mg = blockIdx.x >> 6, rg = blockIdx.x & 63;
    int b0 = mg*16, r0 = rg*8;
    int lr = lane & 15, kq = lane >> 4, kg = kq*8;
    int c = w*16 + lr;                    // block col 0..47 = gate*8 + (r-r0)
    int gate = c >> 3, rcol = r0 + (c & 7);
    const u16* Ap = h_in + (size_t)(b0 + lr)*512 + kg;
    const u16* Bp = WT_h + ((size_t)gate*512 + rcol)*512 + kg;
    f32x4 acc = (f32x4){0.f,0.f,0.f,0.f};
    #pragma unroll
    for (int k0 = 0; k0 < 512; k0 += 32){
        short8 a  = *(const short8*)(Ap + k0);
        short8 bf = *(const short8*)(Bp + k0);
        acc = __builtin_amdgcn_mfma_f32_16x16x32_bf16(a, bf, acc, 0,0,0);
    }
    #pragma unroll
    for (int rr = 0; rr < 4; ++rr)
        gates[(kq*4+rr)*GP3 + c] = acc[rr];
    __syncthreads();
    if (tid < 128){
        int ri = tid >> 3, rr = tid & 7;
        int b = b0 + ri, r = r0 + rr;
        const float* wp = wgb + (((size_t)t*64 + b)*512 + r)*6;
        float2 w01 = *(const float2*)(wp);
        float2 w23 = *(const float2*)(wp + 2);
        float2 w45 = *(const float2*)(wp + 4);
        float g0 = gates[ri*GP3 +      rr] + w01.x;
        float g1 = gates[ri*GP3 +  8 + rr] + w01.y;
        float g2 = gates[ri*GP3 + 16 + rr] + w23.x;
        float g3 = gates[ri*GP3 + 24 + rr] + w23.y;
        float g4 = gates[ri*GP3 + 32 + rr] + w45.x;
        float g5 = gates[ri*GP3 + 40 + rr] + w45.y;
        float ig = sigf(g0), fg = sigf(g1), og = sigf(g2), sg = sigf(g3);
        float cell = fmaxf(g4, g5);
        float co = cstate[b*512 + r];
        float cy = tanhf_(fg*co + ig*cell);
        cstate[b*512 + r] = cy;
        float sent = sg*cy, hy = og*cy;
        h_out[(size_t)b*512 + r] = f2b(hy);
        size_t rgl = (size_t)b*20 + t;
        sent_all[rgl*512 + r] = f2b(sent);
        hy_all[rgl*512 + r]   = f2b(hy);
    }
}

// ---------------- attention scores: grid (1280, 4); chunk c handles a ≡ c (mod 4) ----------------
__global__ __launch_bounds__(256) void attn_score(const u16* __restrict__ sembb, const float* __restrict__ h_emb,
                                                  const u16* __restrict__ p_att,
                                                  const void* __restrict__ W_al, const void* __restrict__ b_al,
                                                  float* __restrict__ evg, const int* __restrict__ dflag){
    __shared__ float he_s[512];
    __shared__ float wal_s[512];
    bool f32 = (*dflag != 0);
    int flat = blockIdx.x;
    int row = (flat & 7)*160 + (flat >> 3);   // XCD-clustered rows (1280 = 8*160)
    int b = row / 20;
    int chunk = blockIdx.y;
    int tid = threadIdx.x, lane = tid & 63, w = tid >> 6;
    for (int d = tid; d < 512; d += 256){
        int ad = ((d & 7) >> 1)*128 + (d >> 3)*2 + (d & 1);
        he_s[ad]  = h_emb[(size_t)row*512 + d];
        wal_s[ad] = ldx(W_al, d, f32);
    }
    __syncthreads();
    float bal = ldx(b_al, 0, f32);
    float* evr = evg + (size_t)row*256;

    for (int j = w; chunk + 4*j < 197; j += 8){
        int a0i = chunk + 4*j;
        int a1i = a0i + 16;
        bool has2 = (a1i < 197);
        const u16* r0 = (a0i == 0) ? (sembb + (size_t)row*512)
                                   : (p_att + ((size_t)(b*196 + a0i-1))*512);
        const u16* r1 = has2 ? (p_att + ((size_t)(b*196 + a1i-1))*512) : r0;
        short8 v0 = *(const short8*)(r0 + lane*8);
        short8 v1 = *(const short8*)(r1 + lane*8);
        const u32* pk0 = (const u32*)&v0;
        const u32* pk1 = (const u32*)&v1;
        float p0 = 0.f, p1 = 0.f;
        #pragma unroll
        for (int jp = 0; jp < 4; ++jp){
            float2 he2 = *(const float2*)&he_s[jp*128 + lane*2];
            float2 wa2 = *(const float2*)&wal_s[jp*128 + lane*2];
            u32 u0 = pk0[jp], u1 = pk1[jp];
            float x00 = __uint_as_float(u0 << 16)          + he2.x;
            float x01 = __uint_as_float(u0 & 0xFFFF0000u)  + he2.y;
            float x10 = __uint_as_float(u1 << 16)          + he2.x;
            float x11 = __uint_as_float(u1 & 0xFFFF0000u)  + he2.y;
            p0 += tanhf_(x00)*wa2.x;
            p0 += tanhf_(x01)*wa2.y;
            p1 += tanhf_(x10)*wa2.x;
            p1 += tanhf_(x11)*wa2.y;
        }
        #pragma unroll
        for (int off = 32; off; off >>= 1){
            p0 += __shfl_xor(p0, off);
            p1 += __shfl_xor(p1, off);
        }
        if (lane == 0){
            evr[a0i] = p0 + bal;
            if (has2) evr[a1i] = p1 + bal;
        }
    }
}

// ---------------- attention ctx: softmax over 197 + cHat + h_lin -> ctx ----------------
__global__ __launch_bounds__(256) void attn_ctx(const float* __restrict__ evg,
                                                const float* __restrict__ sent_lin_f, const float* __restrict__ h_lin_f,
                                                const u16* __restrict__ af,
                                                u16* __restrict__ ctx_in){
    __shared__ float ev[208];
    __shared__ float red2[2];
    int flat = blockIdx.x;
    int row = (flat & 7)*160 + (flat >> 3);
    int b = row / 20;
    int tid = threadIdx.x, lane = tid & 63, w = tid >> 6;
    const float* evr = evg + (size_t)row*256;
    for (int a = tid; a < 197; a += 256) ev[a] = evr[a];
    __syncthreads();
    if (w == 0){
        float m = -1e30f;
        for (int a = lane; a < 197; a += 64) m = fmaxf(m, ev[a]);
        #pragma unroll
        for (int off = 32; off; off >>= 1) m = fmaxf(m, __shfl_xor(m, off));
        float s = 0.f;
        for (int a = lane; a < 197; a += 64) s += __expf(ev[a] - m);
        #pragma unroll
        for (int off = 32; off; off >>= 1) s += __shfl_xor(s, off);
        if (lane == 0){ red2[0] = m; red2[1] = __builtin_amdgcn_rcpf(s); }
    }
    __syncthreads();
    float m = red2[0], inv = red2[1];
    for (int a = tid; a < 197; a += 256) ev[a] = __expf(ev[a] - m) * inv;
    __syncthreads();

    int d = tid*2;
    const u16* afb = af + (size_t)b*196*512 + d;
    float s0 = 0.f, s1 = 0.f, t0 = 0.f, t1 = 0.f;
    for (int a = 0; a < 196; a += 2){
        float e0 = ev[a+1], e1 = ev[a+2];
        u32 u0 = *(const u32*)(afb + (size_t)a*512);
        u32 u1 = *(const u32*)(afb + (size_t)(a+1)*512);
        s0 += e0 * __uint_as_float(u0 << 16);
        s1 += e0 * __uint_as_float(u0 & 0xFFFF0000u);
        t0 += e1 * __uint_as_float(u1 << 16);
        t1 += e1 * __uint_as_float(u1 & 0xFFFF0000u);
    }
    float e00 = ev[0];
    float a0 = e00*sent_lin_f[(size_t)row*512 + d]     + s0 + t0 + h_lin_f[(size_t)row*512 + d];
    float a1 = e00*sent_lin_f[(size_t)row*512 + d + 1] + s1 + t1 + h_lin_f[(size_t)row*512 + d + 1];
    ctx_in[(size_t)row*512 + d]     = f2b(a0);
    ctx_in[(size_t)row*512 + d + 1] = f2b(a1);
}

// ---------------- row log-softmax over 7800: single global read, row cached in regs ----------------
__global__ __launch_bounds__(256) void logsoftmax_kernel(const u16* __restrict__ logits, void* __restrict__ out,
                                                         const int* __restrict__ dflag){
    __shared__ float red[256];
    bool f32 = (*dflag != 0);
    int row = blockIdx.x, tid = threadIdx.x;
    const u16* lp = logits + (size_t)row*7808;
    float xs[31];
    float m = -1e30f;
    #pragma unroll
    for (int k = 0; k < 31; ++k){
        int v = k*256 + tid;
        xs[k] = (v < 7800) ? b2f(lp[v]) : -1e30f;
        m = fmaxf(m, xs[k]);
    }
    red[tid] = m; __syncthreads();
    for (int s = 128; s; s >>= 1){ if (tid < s) red[tid] = fmaxf(red[tid], red[tid+s]); __syncthreads(); }
    m = red[0]; __syncthreads();
    float s = 0.f;
    #pragma unroll
    for (int k = 0; k < 31; ++k) s += __expf(xs[k] - m);
    red[tid] = s; __syncthreads();
    for (int st = 128; st; st >>= 1){ if (tid < st) red[tid] += red[tid+st]; __syncthreads(); }
    float lse = m + __logf(red[0]);
    if (f32){
        float* op = (float*)out + (size_t)row*7800;
        #pragma unroll
        for (int k = 0; k < 31; ++k){
            int v = k*256 + tid;
            if (v < 7800) op[v] = xs[k] - lse;
        }
    } else {
        u16* op = (u16*)out + (size_t)row*7800;
        #pragma unroll
        for (int k = 0; k < 31; ++k){
            int v = k*256 + tid;
            if (v < 7800) op[v] = f2b(xs[k] - lse);
        }
    }
}

extern "C" void kernel_launch(void* const* d_in, const int* in_sizes, int n_in,
                              void* d_out, int out_size, void* d_ws, size_t ws_size,
                              hipStream_t stream){
    (void)in_sizes; (void)n_in; (void)out_size; (void)ws_size;
    const int* seq    = (const int*)d_in[0];
    const void* att   = d_in[1];
    const void* embed = d_in[2];
    const void* W_word= d_in[3];  const void* b_word = d_in[4];
    const void* W_h   = d_in[5];  const void* b_h    = d_in[6];
    const void* W_img = d_in[7];  const void* b_img  = d_in[8];
    const void* W_ae  = d_in[9];  const void* b_ae   = d_in[10];
    const void* W_c2a = d_in[11]; const void* b_c2a  = d_in[12];
    const void* W_sl  = d_in[13]; const void* b_sl   = d_in[14];
    const void* W_se  = d_in[15]; const void* b_se   = d_in[16];
    const void* W_hl  = d_in[17]; const void* b_hl   = d_in[18];
    const void* W_he  = d_in[19]; const void* b_he   = d_in[20];
    const void* W_al  = d_in[21]; const void* b_al   = d_in[22];
    const void* W_a2h = d_in[23]; const void* b_a2h  = d_in[24];
    const void* W_log = d_in[25]; const void* b_log  = d_in[26];

    char* p = (char*)d_ws;
    auto alloc = [&](size_t bytes)->char*{ char* r = p; p += (bytes + 255) & ~(size_t)255; return r; };

    int* dflag   = (int*)alloc(256);
    u16* WT_ae   = (u16*)alloc((size_t)512*2048*2);
    u16* WT_word = (u16*)alloc((size_t)3072*512*2);
    u16* WT_h    = (u16*)alloc((size_t)3072*512*2);
    u16* WT_img  = (u16*)alloc((size_t)3072*512*2);
    u16* WT_c2a  = (u16*)alloc((size_t)512*512*2);
    u16* WT_sl   = (u16*)alloc((size_t)512*512*2);
    u16* WT_se   = (u16*)alloc((size_t)512*512*2);
    u16* WT_hl   = (u16*)alloc((size_t)512*512*2);
    u16* WT_he   = (u16*)alloc((size_t)512*512*2);
    u16* WT_a2h  = (u16*)alloc((size_t)512*512*2);
    u16* WT_log  = (u16*)alloc((size_t)7808*512*2);
    u16* af      = (u16*)alloc((size_t)12544*512*2);
    u16* p_att   = (u16*)alloc((size_t)12544*512*2);
    u16* meanb   = (u16*)alloc((size_t)64*512*2);
    float* imgg  = (float*)alloc((size_t)64*3072*4);
    u16* xemb    = (u16*)alloc((size_t)1280*512*2);
    float* wgb   = (float*)alloc((size_t)1280*3072*4);   // [t][b][512][6] layout
    u16* hb0     = (u16*)alloc((size_t)64*512*2);
    u16* hb1     = (u16*)alloc((size_t)64*512*2);
    float* cst   = (float*)alloc((size_t)64*512*4);
    u16* sent_all= (u16*)alloc((size_t)1280*512*2);
    u16* hy_all  = (u16*)alloc((size_t)1280*512*2);
    float* slf   = (float*)alloc((size_t)1280*512*4);
    u16* slb     = (u16*)alloc((size_t)1280*512*2);
    float* hlf   = (float*)alloc((size_t)1280*512*4);
    u16* hlb     = (u16*)alloc((size_t)1280*512*2);
    u16* sembb   = (u16*)alloc((size_t)1280*512*2);
    float* hemb  = (float*)alloc((size_t)1280*512*4);
    u16* ctx     = (u16*)alloc((size_t)1280*512*2);
    u16* a2hb    = (u16*)alloc((size_t)1280*512*2);
    float* evg   = (float*)alloc((size_t)1280*256*4);
    u16* logits  = (u16*)alloc((size_t)1280*7808*2);

    probe_dtype<<<1, 64, 0, stream>>>(W_ae, dflag);

    dim3 tb(32,8);
    {
        TP t6{};
        t6.src[0]=W_c2a; t6.dst[0]=WT_c2a;
        t6.src[1]=W_sl;  t6.dst[1]=WT_sl;
        t6.src[2]=W_se;  t6.dst[2]=WT_se;
        t6.src[3]=W_hl;  t6.dst[3]=WT_hl;
        t6.src[4]=W_he;  t6.dst[4]=WT_he;
        t6.src[5]=W_a2h; t6.dst[5]=WT_a2h;
        transpose_multi<<<dim3(16,16,6), tb, 0, stream>>>(t6, 512, 512, 512, dflag);
        TP t3{};
        t3.src[0]=W_word; t3.dst[0]=WT_word;
        t3.src[1]=W_h;    t3.dst[1]=WT_h;
        t3.src[2]=W_img;  t3.dst[2]=WT_img;
        transpose_multi<<<dim3(96,16,3), tb, 0, stream>>>(t3, 512, 3072, 3072, dflag);
        TP ta{}; ta.src[0]=W_ae; ta.dst[0]=WT_ae;
        transpose_multi<<<dim3(16,64,1), tb, 0, stream>>>(ta, 2048, 512, 512, dflag);
        TP tl{}; tl.src[0]=W_log; tl.dst[0]=WT_log;
        transpose_multi<<<dim3(244,16,1), tb, 0, stream>>>(tl, 512, 7800, 7808, dflag);
    }

    // af = relu(att @ W_ae + b_ae) -- fused f32->bf16 reg-staged A (no convert pass)
    gemm_aff<<<dim3(8,98), 256, 0, stream>>>(att, WT_ae, 512, 2048, b_ae, af, 512, 12544, dflag);
    // p_att = af @ W_c2a + b_c2a
    gemm_tn<128><<<dim3(8,98), 256, 0, stream>>>(af, WT_c2a, 512, 512,
                                                 b_c2a, nullptr, nullptr, 1, nullptr, p_att, 0, 512, 12544, dflag, 0);
    mean_af_kernel<<<64, 256, 0, stream>>>(af, meanb);
    gemm_tn<64><<<dim3(48,1), 256, 0, stream>>>(meanb, WT_img, 3072, 512,
                                                b_img, nullptr, nullptr, 1, imgg, nullptr, 0, 3072, 64, dflag, 0);
    gather_emb<<<2560, 256, 0, stream>>>(seq, embed, xemb, dflag);
    // wgb[t][b][r][6] = x_emb @ W_word + b_word + b_h + img_gate[b]
    gemm_tn<64><<<dim3(48,20), 256, 0, stream>>>(xemb, WT_word, 3072, 512,
                                                 b_word, b_h, imgg, 20, wgb, nullptr, 0, 3072, 1280, dflag, 1);

    hipMemsetAsync(hb0, 0, (size_t)64*512*2, stream);
    hipMemsetAsync(cst, 0, (size_t)64*512*4, stream);

    // sequential recurrence, per-step launches; 256 blocks x 192 thr each
    for (int t = 0; t < 20; ++t){
        const u16* hin = (t & 1) ? hb1 : hb0;
        u16* hout      = (t & 1) ? hb0 : hb1;
        lstm_step<<<256, 192, 0, stream>>>(hin, WT_h, wgb, cst, hout, sent_all, hy_all, t);
    }

    // post-recurrence, z-batched pairs
    GP2 pa{};
    pa.g[0] = { sent_all, WT_sl, b_sl, slf, slb, 1 };
    pa.g[1] = { hy_all,   WT_hl, b_hl, hlf, hlb, 2 };
    gemm_tn2<<<dim3(8,20,2), 256, 0, stream>>>(pa, 512, 512, 512, 1280, dflag);
    GP2 pb{};
    pb.g[0] = { slb, WT_se, b_se, nullptr, sembb, 0 };
    pb.g[1] = { hlb, WT_he, b_he, hemb, nullptr, 0 };
    gemm_tn2<<<dim3(8,20,2), 256, 0, stream>>>(pb, 512, 512, 512, 1280, dflag);

    // attention: high-occupancy score pass, then softmax+ctx pass
    attn_score<<<dim3(1280,4), 256, 0, stream>>>(sembb, hemb, p_att, W_al, b_al, evg, dflag);
    attn_ctx<<<1280, 256, 0, stream>>>(evg, slf, hlf, af, ctx);

    gemm_tn<64><<<dim3(8,20), 256, 0, stream>>>(ctx, WT_a2h, 512, 512,
                                                b_a2h, nullptr, nullptr, 1, nullptr, a2hb, 2, 512, 1280, dflag, 0);
    gemm_tn<128><<<dim3(122,10), 256, 0, stream>>>(a2hb, WT_log, 7808, 512,
                                                   b_log, nullptr, nullptr, 1, nullptr, logits, 0, 7800, 1280, dflag, 0);
    logsoftmax_kernel<<<1280, 256, 0, stream>>>(logits, d_out, dflag);
}

// Round 15
// 409.544 us; speedup vs baseline: 1.0339x; 1.0339x over previous
//
#include <hip/hip_runtime.h>

using short8 = __attribute__((ext_vector_type(8))) short;
using f32x4  = __attribute__((ext_vector_type(4))) float;
typedef unsigned short u16;
typedef unsigned int u32;

__device__ __forceinline__ float b2f(u16 u){
    return __uint_as_float(((u32)u) << 16);
}
__device__ __forceinline__ u16 f2b(float f){
    u32 x = __float_as_uint(f);
    u32 r = (x + 0x7FFFu + ((x >> 16) & 1u)) >> 16;
    return (u16)r;
}
__device__ __forceinline__ float ldx(const void* p, size_t i, bool f32){
    return f32 ? ((const float*)p)[i] : b2f(((const u16*)p)[i]);
}
__device__ __forceinline__ float sigf(float x){
    return __builtin_amdgcn_rcpf(1.0f + __expf(-x));
}
__device__ __forceinline__ float tanhf_(float x){
    float e = __expf(2.0f*x);
    return 1.0f - 2.0f*__builtin_amdgcn_rcpf(e + 1.0f);
}

#define GLDS(g, l) __builtin_amdgcn_global_load_lds((const __attribute__((address_space(1))) void*)(g), \
                        (__attribute__((address_space(3))) void*)(l), 16, 0, 0)

// ---------------- dtype probe ----------------
__global__ void probe_dtype(const void* w, int* flag){
    const u16* up = (const u16*)w;
    int lane = threadIdx.x & 63;
    int cnt = 0;
    for (int i = lane; i < 256; i += 64){
        u16 u = up[2*i];
        int e = (u >> 7) & 0xFF;
        if (e >= 100 && e <= 126) cnt++;
    }
    #pragma unroll
    for (int off = 32; off; off >>= 1) cnt += __shfl_xor(cnt, off);
    if (lane == 0) *flag = (cnt >= 192) ? 0 : 1;   // 1 == inputs are f32
}

// ---------------- convert att (f32 or bf16) -> bf16, 8 elems/thread ----------------
__global__ __launch_bounds__(256) void convert_att(const void* __restrict__ in, u16* __restrict__ out,
                                                   const int* __restrict__ dflag, int total8){
    bool f32 = (*dflag != 0);
    int i = blockIdx.x*256 + threadIdx.x;
    if (i >= total8) return;
    size_t e = (size_t)i*8;
    if (f32){
        const float4* p = (const float4*)((const float*)in + e);
        float4 v0 = p[0], v1 = p[1];
        u16 o[8] = { f2b(v0.x),f2b(v0.y),f2b(v0.z),f2b(v0.w),
                     f2b(v1.x),f2b(v1.y),f2b(v1.z),f2b(v1.w) };
        *(uint4*)(out + e) = *(const uint4*)o;
    } else {
        *(uint4*)(out + e) = *(const uint4*)((const u16*)in + e);
    }
}

// ---------------- multi transpose (K,N)->(Npad,K), up to 8 weights per launch ----------------
struct TP { const void* src[8]; u16* dst[8]; };
__global__ __launch_bounds__(256) void transpose_multi(TP tp, int K, int N, int Npad,
                                                       const int* __restrict__ dflag){
    __shared__ u16 tile[32][33];
    bool f32 = (*dflag != 0);
    const void* in = tp.src[blockIdx.z];
    u16* out = tp.dst[blockIdx.z];
    int bx = blockIdx.x, by = blockIdx.y;
    int tx = threadIdx.x, ty = threadIdx.y;   // (32,8)
    int n = bx*32 + tx;
    #pragma unroll
    for (int i = 0; i < 32; i += 8){
        int k = by*32 + ty + i;
        u16 v = 0;
        if (n < N && k < K)
            v = f32 ? f2b(((const float*)in)[(size_t)k*N + n]) : ((const u16*)in)[(size_t)k*N + n];
        tile[ty+i][tx] = v;
    }
    __syncthreads();
    int k2 = by*32 + tx;
    #pragma unroll
    for (int i = 0; i < 32; i += 8){
        int n2 = bx*32 + ty + i;
        if (n2 < Npad && k2 < K) out[(size_t)n2*K + k2] = tile[tx][ty+i];
    }
}

// ---------------- embedding gather + relu -> bf16 ----------------
__global__ __launch_bounds__(256) void gather_emb(const int* __restrict__ seq, const void* __restrict__ embed,
                                                  u16* __restrict__ x_emb, const int* __restrict__ dflag){
    bool f32 = (*dflag != 0);
    int idx = blockIdx.x*256 + threadIdx.x;
    if (idx >= 1280*512) return;
    int row = idx >> 9, r = idx & 511;
    int b = row / 20, t = row % 20;
    int w = seq[b*21 + t];
    float v = ldx(embed, (size_t)w*512 + r, f32);
    x_emb[idx] = f2b(fmaxf(v, 0.f));
}

// ---------------- mean over A of af -> bf16 ----------------
__global__ __launch_bounds__(256) void mean_af_kernel(const u16* __restrict__ af, u16* __restrict__ mean_af){
    int b = blockIdx.x, tid = threadIdx.x;
    for (int r = tid; r < 512; r += 256){
        float s = 0.f;
        for (int a = 0; a < 196; ++a) s += b2f(af[((size_t)(b*196+a))*512 + r]);
        mean_af[b*512+r] = f2b(s * (1.0f/196.0f));
    }
}

// ---------------- MFMA GEMM: A(M,K) bf16, BT(Npad,K) bf16; tile TM x 64, BK=64 ----------------
// perm: if 1, C index remapped for wgb: row b*20+t -> t*64+b, col gate*512+r -> r*6+gate
template<int TM>
__global__ __launch_bounds__(256) void gemm_tn(const u16* __restrict__ A, const u16* __restrict__ BT,
                                               int N, int K,
                                               const void* __restrict__ bias1, const void* __restrict__ bias2,
                                               const float* __restrict__ rowAdd, int rowDiv,
                                               float* __restrict__ Cf, u16* __restrict__ Cb,
                                               int act, int Nvalid, int Mvalid,
                                               const int* __restrict__ dflag, int perm){
    constexpr int MW = TM/64;
    __shared__ u16 As[TM*64];
    __shared__ u16 Bs[64*64];
    bool f32 = (*dflag != 0);
    int tid = threadIdx.x, lane = tid & 63, w = tid >> 6;
    int lr = lane & 15, kq = lane >> 4;

    int gN = gridDim.x;
    int nwg = gN * gridDim.y;
    int flat = blockIdx.y*gN + blockIdx.x;
    int q = nwg >> 3, r = nwg & 7;
    int xcd = flat & 7, pos = flat >> 3;
    int wgid = (xcd < r ? xcd*(q+1) : r*(q+1) + (xcd-r)*q) + pos;
    int bm = wgid / gN, bn = wgid % gN;
    int row0 = bm*TM, col0 = bn*64;

    f32x4 acc[MW][4];
    #pragma unroll
    for (int m=0;m<MW;++m)
        #pragma unroll
        for (int n=0;n<4;++n) acc[m][n] = (f32x4){0.f,0.f,0.f,0.f};

    for (int k0 = 0; k0 < K; k0 += 64){
        #pragma unroll
        for (int i=0;i<TM/32;++i){
            int c = i*256 + tid;
            int row = c>>3, slot = (c&7) ^ (row&7);
            GLDS((const char*)A + ((size_t)(row0+row)*K + k0)*2 + slot*16,
                 As + (size_t)(i*256 + w*64)*8);
        }
        #pragma unroll
        for (int i=0;i<2;++i){
            int c = i*256 + tid;
            int row = c>>3, slot = (c&7) ^ (row&7);
            GLDS((const char*)BT + ((size_t)(col0+row)*K + k0)*2 + slot*16,
                 Bs + (size_t)(i*256 + w*64)*8);
        }
        __syncthreads();
        short8 av[MW][2], bv[4][2];
        #pragma unroll
        for (int ks=0;ks<2;++ks){
            #pragma unroll
            for (int m=0;m<MW;++m){
                int rrow = w*(TM/4) + m*16 + lr;
                int sl = (ks*4+kq) ^ (rrow&7);
                av[m][ks] = *(const short8*)(As + rrow*64 + sl*8);
            }
            #pragma unroll
            for (int n=0;n<4;++n){
                int rrow = n*16 + lr;
                int sl = (ks*4+kq) ^ (rrow&7);
                bv[n][ks] = *(const short8*)(Bs + rrow*64 + sl*8);
            }
        }
        #pragma unroll
        for (int ks=0;ks<2;++ks)
            #pragma unroll
            for (int m=0;m<MW;++m)
                #pragma unroll
                for (int n=0;n<4;++n)
                    acc[m][n] = __builtin_amdgcn_mfma_f32_16x16x32_bf16(av[m][ks], bv[n][ks], acc[m][n], 0,0,0);
        __syncthreads();
    }

    #pragma unroll
    for (int n=0;n<4;++n){
        int col = col0 + n*16 + lr;
        float bvv = 0.f;
        if (col < Nvalid){
            if (bias1) bvv += ldx(bias1, col, f32);
            if (bias2) bvv += ldx(bias2, col, f32);
        }
        #pragma unroll
        for (int m=0;m<MW;++m){
            #pragma unroll
            for (int rr=0;rr<4;++rr){
                int row = row0 + w*(TM/4) + m*16 + kq*4 + rr;
                if (row < Mvalid && col < Nvalid){
                    float v = acc[m][n][rr] + bvv;
                    if (rowAdd) v += rowAdd[(size_t)(row/rowDiv)*N + col];
                    if (act == 1) v = fmaxf(v, 0.f);
                    else if (act == 2) v = tanhf_(v);
                    size_t o;
                    if (perm){
                        int orow = (row % 20)*64 + row/20;
                        int ocol = (col & 511)*6 + (col >> 9);
                        o = (size_t)orow*N + ocol;
                    } else {
                        o = (size_t)row*N + col;
                    }
                    if (Cf) Cf[o] = v;
                    if (Cb) Cb[o] = f2b(v);
                }
            }
        }
    }
}

// ---------------- z-batched pair of 512x512 GEMMs (M=1280), TM=64 ----------------
struct GP { const u16* A; const u16* BT; const void* b1; float* Cf; u16* Cb; int act; };
struct GP2 { GP g[2]; };
__global__ __launch_bounds__(256) void gemm_tn2(GP2 ps, int N, int K, int Nvalid, int Mvalid,
                                                const int* __restrict__ dflag){
    __shared__ u16 As[64*64];
    __shared__ u16 Bs[64*64];
    bool f32 = (*dflag != 0);
    GP gp = ps.g[blockIdx.z];
    int tid = threadIdx.x, lane = tid & 63, w = tid >> 6;
    int lr = lane & 15, kq = lane >> 4;

    int gN = gridDim.x;
    int nwg = gN * gridDim.y;
    int flat = blockIdx.y*gN + blockIdx.x;
    int q = nwg >> 3, r = nwg & 7;
    int xcd = flat & 7, pos = flat >> 3;
    int wgid = (xcd < r ? xcd*(q+1) : r*(q+1) + (xcd-r)*q) + pos;
    int bm = wgid / gN, bn = wgid % gN;
    int row0 = bm*64, col0 = bn*64;

    f32x4 acc[4];
    #pragma unroll
    for (int n=0;n<4;++n) acc[n] = (f32x4){0.f,0.f,0.f,0.f};

    for (int k0 = 0; k0 < K; k0 += 64){
        {
            int c = tid;
            int row = c>>3, slot = (c&7) ^ (row&7);
            GLDS((const char*)gp.A + ((size_t)(row0+row)*K + k0)*2 + slot*16,
                 As + (size_t)(w*64)*8);
            c = 256 + tid;
            row = c>>3; slot = (c&7) ^ (row&7);
            GLDS((const char*)gp.A + ((size_t)(row0+row)*K + k0)*2 + slot*16,
                 As + (size_t)(256 + w*64)*8);
            c = tid;
            row = c>>3; slot = (c&7) ^ (row&7);
            GLDS((const char*)gp.BT + ((size_t)(col0+row)*K + k0)*2 + slot*16,
                 Bs + (size_t)(w*64)*8);
            c = 256 + tid;
            row = c>>3; slot = (c&7) ^ (row&7);
            GLDS((const char*)gp.BT + ((size_t)(col0+row)*K + k0)*2 + slot*16,
                 Bs + (size_t)(256 + w*64)*8);
        }
        __syncthreads();
        short8 av[2], bv[4][2];
        #pragma unroll
        for (int ks=0;ks<2;++ks){
            int rrow = w*16 + lr;
            int sl = (ks*4+kq) ^ (rrow&7);
            av[ks] = *(const short8*)(As + rrow*64 + sl*8);
            #pragma unroll
            for (int n=0;n<4;++n){
                int rr2 = n*16 + lr;
                int sl2 = (ks*4+kq) ^ (rr2&7);
                bv[n][ks] = *(const short8*)(Bs + rr2*64 + sl2*8);
            }
        }
        #pragma unroll
        for (int ks=0;ks<2;++ks)
            #pragma unroll
            for (int n=0;n<4;++n)
                acc[n] = __builtin_amdgcn_mfma_f32_16x16x32_bf16(av[ks], bv[n][ks], acc[n], 0,0,0);
        __syncthreads();
    }

    #pragma unroll
    for (int n=0;n<4;++n){
        int col = col0 + n*16 + lr;
        float bvv = (col < Nvalid && gp.b1) ? ldx(gp.b1, col, f32) : 0.f;
        #pragma unroll
        for (int rr=0;rr<4;++rr){
            int row = row0 + w*16 + kq*4 + rr;
            if (row < Mvalid && col < Nvalid){
                float v = acc[n][rr] + bvv;
                if (gp.act == 1) v = fmaxf(v, 0.f);
                else if (gp.act == 2) v = tanhf_(v);
                size_t o = (size_t)row*N + col;
                if (gp.Cf) gp.Cf[o] = v;
                if (gp.Cb) gp.Cb[o] = f2b(v);
            }
        }
    }
}

// ---------------- LSTM step v3: 256 blocks x 192 thr; wgb in [t][b][r][6] layout ----------------
#define GP3 52
__global__ __launch_bounds__(192) void lstm_step(const u16* __restrict__ h_in, const u16* __restrict__ WT_h,
                                                 const float* __restrict__ wgb, float* __restrict__ cstate,
                                                 u16* __restrict__ h_out, u16* __restrict__ sent_all,
                                                 u16* __restrict__ hy_all, int t){
    __shared__ float gates[16*GP3];
    int tid = threadIdx.x, lane = tid & 63, w = tid >> 6;   // w in 0..2
    int mg = blockIdx.x >> 6, rg = blockIdx.x & 63;
    int b0 = mg*16, r0 = rg*8;
    int lr = lane & 15, kq = lane >> 4, kg = kq*8;
    int c = w*16 + lr;                    // block col 0..47 = gate*8 + (r-r0)
    int gate = c >> 3, rcol = r0 + (c & 7);
    const u16* Ap = h_in + (size_t)(b0 + lr)*512 + kg;
    const u16* Bp = WT_h + ((size_t)gate*512 + rcol)*512 + kg;
    f32x4 acc = (f32x4){0.f,0.f,0.f,0.f};
    #pragma unroll
    for (int k0 = 0; k0 < 512; k0 += 32){
        short8 a  = *(const short8*)(Ap + k0);
        short8 bf = *(const short8*)(Bp + k0);
        acc = __builtin_amdgcn_mfma_f32_16x16x32_bf16(a, bf, acc, 0,0,0);
    }
    #pragma unroll
    for (int rr = 0; rr < 4; ++rr)
        gates[(kq*4+rr)*GP3 + c] = acc[rr];
    __syncthreads();
    if (tid < 128){
        int ri = tid >> 3, rr = tid & 7;
        int b = b0 + ri, r = r0 + rr;
        const float* wp = wgb + (((size_t)t*64 + b)*512 + r)*6;
        float2 w01 = *(const float2*)(wp);
        float2 w23 = *(const float2*)(wp + 2);
        float2 w45 = *(const float2*)(wp + 4);
        float g0 = gates[ri*GP3 +      rr] + w01.x;
        float g1 = gates[ri*GP3 +  8 + rr] + w01.y;
        float g2 = gates[ri*GP3 + 16 + rr] + w23.x;
        float g3 = gates[ri*GP3 + 24 + rr] + w23.y;
        float g4 = gates[ri*GP3 + 32 + rr] + w45.x;
        float g5 = gates[ri*GP3 + 40 + rr] + w45.y;
        float ig = sigf(g0), fg = sigf(g1), og = sigf(g2), sg = sigf(g3);
        float cell = fmaxf(g4, g5);
        float co = cstate[b*512 + r];
        float cy = tanhf_(fg*co + ig*cell);
        cstate[b*512 + r] = cy;
        float sent = sg*cy, hy = og*cy;
        h_out[(size_t)b*512 + r] = f2b(hy);
        size_t rgl = (size_t)b*20 + t;
        sent_all[rgl*512 + r] = f2b(sent);
        hy_all[rgl*512 + r]   = f2b(hy);
    }
}

// ---------------- attention scores: grid (1280, 4); chunk c handles a ≡ c (mod 4) ----------------
__global__ __launch_bounds__(256) void attn_score(const u16* __restrict__ sembb, const float* __restrict__ h_emb,
                                                  const u16* __restrict__ p_att,
                                                  const void* __restrict__ W_al, const void* __restrict__ b_al,
                                                  float* __restrict__ evg, const int* __restrict__ dflag){
    __shared__ float he_s[512];
    __shared__ float wal_s[512];
    bool f32 = (*dflag != 0);
    int flat = blockIdx.x;
    int row = (flat & 7)*160 + (flat >> 3);   // XCD-clustered rows (1280 = 8*160)
    int b = row / 20;
    int chunk = blockIdx.y;
    int tid = threadIdx.x, lane = tid & 63, w = tid >> 6;
    for (int d = tid; d < 512; d += 256){
        int ad = ((d & 7) >> 1)*128 + (d >> 3)*2 + (d & 1);
        he_s[ad]  = h_emb[(size_t)row*512 + d];
        wal_s[ad] = ldx(W_al, d, f32);
    }
    __syncthreads();
    float bal = ldx(b_al, 0, f32);
    float* evr = evg + (size_t)row*256;

    for (int j = w; chunk + 4*j < 197; j += 8){
        int a0i = chunk + 4*j;
        int a1i = a0i + 16;
        bool has2 = (a1i < 197);
        const u16* r0 = (a0i == 0) ? (sembb + (size_t)row*512)
                                   : (p_att + ((size_t)(b*196 + a0i-1))*512);
        const u16* r1 = has2 ? (p_att + ((size_t)(b*196 + a1i-1))*512) : r0;
        short8 v0 = *(const short8*)(r0 + lane*8);
        short8 v1 = *(const short8*)(r1 + lane*8);
        const u32* pk0 = (const u32*)&v0;
        const u32* pk1 = (const u32*)&v1;
        float p0 = 0.f, p1 = 0.f;
        #pragma unroll
        for (int jp = 0; jp < 4; ++jp){
            float2 he2 = *(const float2*)&he_s[jp*128 + lane*2];
            float2 wa2 = *(const float2*)&wal_s[jp*128 + lane*2];
            u32 u0 = pk0[jp], u1 = pk1[jp];
            float x00 = __uint_as_float(u0 << 16)          + he2.x;
            float x01 = __uint_as_float(u0 & 0xFFFF0000u)  + he2.y;
            float x10 = __uint_as_float(u1 << 16)          + he2.x;
            float x11 = __uint_as_float(u1 & 0xFFFF0000u)  + he2.y;
            p0 += tanhf_(x00)*wa2.x;
            p0 += tanhf_(x01)*wa2.y;
            p1 += tanhf_(x10)*wa2.x;
            p1 += tanhf_(x11)*wa2.y;
        }
        #pragma unroll
        for (int off = 32; off; off >>= 1){
            p0 += __shfl_xor(p0, off);
            p1 += __shfl_xor(p1, off);
        }
        if (lane == 0){
            evr[a0i] = p0 + bal;
            if (has2) evr[a1i] = p1 + bal;
        }
    }
}

// ---------------- attention ctx: softmax over 197 + cHat + h_lin -> ctx ----------------
__global__ __launch_bounds__(256) void attn_ctx(const float* __restrict__ evg,
                                                const float* __restrict__ sent_lin_f, const float* __restrict__ h_lin_f,
                                                const u16* __restrict__ af,
                                                u16* __restrict__ ctx_in){
    __shared__ float ev[208];
    __shared__ float red2[2];
    int flat = blockIdx.x;
    int row = (flat & 7)*160 + (flat >> 3);
    int b = row / 20;
    int tid = threadIdx.x, lane = tid & 63, w = tid >> 6;
    const float* evr = evg + (size_t)row*256;
    for (int a = tid; a < 197; a += 256) ev[a] = evr[a];
    __syncthreads();
    if (w == 0){
        float m = -1e30f;
        for (int a = lane; a < 197; a += 64) m = fmaxf(m, ev[a]);
        #pragma unroll
        for (int off = 32; off; off >>= 1) m = fmaxf(m, __shfl_xor(m, off));
        float s = 0.f;
        for (int a = lane; a < 197; a += 64) s += __expf(ev[a] - m);
        #pragma unroll
        for (int off = 32; off; off >>= 1) s += __shfl_xor(s, off);
        if (lane == 0){ red2[0] = m; red2[1] = __builtin_amdgcn_rcpf(s); }
    }
    __syncthreads();
    float m = red2[0], inv = red2[1];
    for (int a = tid; a < 197; a += 256) ev[a] = __expf(ev[a] - m) * inv;
    __syncthreads();

    int d = tid*2;
    const u16* afb = af + (size_t)b*196*512 + d;
    float s0 = 0.f, s1 = 0.f, t0 = 0.f, t1 = 0.f;
    for (int a = 0; a < 196; a += 2){
        float e0 = ev[a+1], e1 = ev[a+2];
        u32 u0 = *(const u32*)(afb + (size_t)a*512);
        u32 u1 = *(const u32*)(afb + (size_t)(a+1)*512);
        s0 += e0 * __uint_as_float(u0 << 16);
        s1 += e0 * __uint_as_float(u0 & 0xFFFF0000u);
        t0 += e1 * __uint_as_float(u1 << 16);
        t1 += e1 * __uint_as_float(u1 & 0xFFFF0000u);
    }
    float e00 = ev[0];
    float a0 = e00*sent_lin_f[(size_t)row*512 + d]     + s0 + t0 + h_lin_f[(size_t)row*512 + d];
    float a1 = e00*sent_lin_f[(size_t)row*512 + d + 1] + s1 + t1 + h_lin_f[(size_t)row*512 + d + 1];
    ctx_in[(size_t)row*512 + d]     = f2b(a0);
    ctx_in[(size_t)row*512 + d + 1] = f2b(a1);
}

// ---------------- row log-softmax over 7800: single global read, row cached in regs ----------------
__global__ __launch_bounds__(256) void logsoftmax_kernel(const u16* __restrict__ logits, void* __restrict__ out,
                                                         const int* __restrict__ dflag){
    __shared__ float red[256];
    bool f32 = (*dflag != 0);
    int row = blockIdx.x, tid = threadIdx.x;
    const u16* lp = logits + (size_t)row*7808;
    float xs[31];
    float m = -1e30f;
    #pragma unroll
    for (int k = 0; k < 31; ++k){
        int v = k*256 + tid;
        xs[k] = (v < 7800) ? b2f(lp[v]) : -1e30f;
        m = fmaxf(m, xs[k]);
    }
    red[tid] = m; __syncthreads();
    for (int s = 128; s; s >>= 1){ if (tid < s) red[tid] = fmaxf(red[tid], red[tid+s]); __syncthreads(); }
    m = red[0]; __syncthreads();
    float s = 0.f;
    #pragma unroll
    for (int k = 0; k < 31; ++k) s += __expf(xs[k] - m);
    red[tid] = s; __syncthreads();
    for (int st = 128; st; st >>= 1){ if (tid < st) red[tid] += red[tid+st]; __syncthreads(); }
    float lse = m + __logf(red[0]);
    if (f32){
        float* op = (float*)out + (size_t)row*7800;
        #pragma unroll
        for (int k = 0; k < 31; ++k){
            int v = k*256 + tid;
            if (v < 7800) op[v] = xs[k] - lse;
        }
    } else {
        u16* op = (u16*)out + (size_t)row*7800;
        #pragma unroll
        for (int k = 0; k < 31; ++k){
            int v = k*256 + tid;
            if (v < 7800) op[v] = f2b(xs[k] - lse);
        }
    }
}

extern "C" void kernel_launch(void* const* d_in, const int* in_sizes, int n_in,
                              void* d_out, int out_size, void* d_ws, size_t ws_size,
                              hipStream_t stream){
    (void)in_sizes; (void)n_in; (void)out_size; (void)ws_size;
    const int* seq    = (const int*)d_in[0];
    const void* att   = d_in[1];
    const void* embed = d_in[2];
    const void* W_word= d_in[3];  const void* b_word = d_in[4];
    const void* W_h   = d_in[5];  const void* b_h    = d_in[6];
    const void* W_img = d_in[7];  const void* b_img  = d_in[8];
    const void* W_ae  = d_in[9];  const void* b_ae   = d_in[10];
    const void* W_c2a = d_in[11]; const void* b_c2a  = d_in[12];
    const void* W_sl  = d_in[13]; const void* b_sl   = d_in[14];
    const void* W_se  = d_in[15]; const void* b_se   = d_in[16];
    const void* W_hl  = d_in[17]; const void* b_hl   = d_in[18];
    const void* W_he  = d_in[19]; const void* b_he   = d_in[20];
    const void* W_al  = d_in[21]; const void* b_al   = d_in[22];
    const void* W_a2h = d_in[23]; const void* b_a2h  = d_in[24];
    const void* W_log = d_in[25]; const void* b_log  = d_in[26];

    char* p = (char*)d_ws;
    auto alloc = [&](size_t bytes)->char*{ char* r = p; p += (bytes + 255) & ~(size_t)255; return r; };

    int* dflag   = (int*)alloc(256);
    u16* WT_ae   = (u16*)alloc((size_t)512*2048*2);
    u16* WT_word = (u16*)alloc((size_t)3072*512*2);
    u16* WT_h    = (u16*)alloc((size_t)3072*512*2);
    u16* WT_img  = (u16*)alloc((size_t)3072*512*2);
    u16* WT_c2a  = (u16*)alloc((size_t)512*512*2);
    u16* WT_sl   = (u16*)alloc((size_t)512*512*2);
    u16* WT_se   = (u16*)alloc((size_t)512*512*2);
    u16* WT_hl   = (u16*)alloc((size_t)512*512*2);
    u16* WT_he   = (u16*)alloc((size_t)512*512*2);
    u16* WT_a2h  = (u16*)alloc((size_t)512*512*2);
    u16* WT_log  = (u16*)alloc((size_t)7808*512*2);
    u16* af      = (u16*)alloc((size_t)12544*512*2);
    u16* p_att   = (u16*)alloc((size_t)12544*512*2);
    u16* meanb   = (u16*)alloc((size_t)64*512*2);
    float* imgg  = (float*)alloc((size_t)64*3072*4);
    u16* xemb    = (u16*)alloc((size_t)1280*512*2);
    float* wgb   = (float*)alloc((size_t)1280*3072*4);   // [t][b][512][6] layout
    u16* hb0     = (u16*)alloc((size_t)64*512*2);
    u16* hb1     = (u16*)alloc((size_t)64*512*2);
    float* cst   = (float*)alloc((size_t)64*512*4);
    u16* sent_all= (u16*)alloc((size_t)1280*512*2);
    u16* hy_all  = (u16*)alloc((size_t)1280*512*2);
    float* slf   = (float*)alloc((size_t)1280*512*4);
    u16* slb     = (u16*)alloc((size_t)1280*512*2);
    float* hlf   = (float*)alloc((size_t)1280*512*4);
    u16* hlb     = (u16*)alloc((size_t)1280*512*2);
    u16* sembb   = (u16*)alloc((size_t)1280*512*2);
    float* hemb  = (float*)alloc((size_t)1280*512*4);
    u16* ctx     = (u16*)alloc((size_t)1280*512*2);
    u16* a2hb    = (u16*)alloc((size_t)1280*512*2);
    float* evg   = (float*)alloc((size_t)1280*256*4);
    u16* logits  = (u16*)alloc((size_t)1280*7808*2);

    // attb (51.4MB) aliases late-lifetime region [wgb .. logits]:
    // written by convert_att, consumed only by af GEMM, dead before wgb is written.
    u16* attb = (u16*)wgb;

    probe_dtype<<<1, 64, 0, stream>>>(W_ae, dflag);

    dim3 tb(32,8);
    {
        TP t6{};
        t6.src[0]=W_c2a; t6.dst[0]=WT_c2a;
        t6.src[1]=W_sl;  t6.dst[1]=WT_sl;
        t6.src[2]=W_se;  t6.dst[2]=WT_se;
        t6.src[3]=W_hl;  t6.dst[3]=WT_hl;
        t6.src[4]=W_he;  t6.dst[4]=WT_he;
        t6.src[5]=W_a2h; t6.dst[5]=WT_a2h;
        transpose_multi<<<dim3(16,16,6), tb, 0, stream>>>(t6, 512, 512, 512, dflag);
        TP t3{};
        t3.src[0]=W_word; t3.dst[0]=WT_word;
        t3.src[1]=W_h;    t3.dst[1]=WT_h;
        t3.src[2]=W_img;  t3.dst[2]=WT_img;
        transpose_multi<<<dim3(96,16,3), tb, 0, stream>>>(t3, 512, 3072, 3072, dflag);
        TP ta{}; ta.src[0]=W_ae; ta.dst[0]=WT_ae;
        transpose_multi<<<dim3(16,64,1), tb, 0, stream>>>(ta, 2048, 512, 512, dflag);
        TP tl{}; tl.src[0]=W_log; tl.dst[0]=WT_log;
        transpose_multi<<<dim3(244,16,1), tb, 0, stream>>>(tl, 512, 7800, 7808, dflag);
    }

    convert_att<<<12544, 256, 0, stream>>>(att, attb, dflag, 12544*2048/8);

    // af = relu(att @ W_ae + b_ae)  -- TM=64, 1568 blocks (occupancy)
    gemm_tn<64><<<dim3(8,196), 256, 0, stream>>>(attb, WT_ae, 512, 2048,
                                                 b_ae, nullptr, nullptr, 1, nullptr, af, 1, 512, 12544, dflag, 0);
    // p_att = af @ W_c2a + b_c2a  -- TM=64
    gemm_tn<64><<<dim3(8,196), 256, 0, stream>>>(af, WT_c2a, 512, 512,
                                                 b_c2a, nullptr, nullptr, 1, nullptr, p_att, 0, 512, 12544, dflag, 0);
    mean_af_kernel<<<64, 256, 0, stream>>>(af, meanb);
    gemm_tn<64><<<dim3(48,1), 256, 0, stream>>>(meanb, WT_img, 3072, 512,
                                                b_img, nullptr, nullptr, 1, imgg, nullptr, 0, 3072, 64, dflag, 0);
    gather_emb<<<2560, 256, 0, stream>>>(seq, embed, xemb, dflag);
    // wgb[t][b][r][6] = x_emb @ W_word + b_word + b_h + img_gate[b]   (perm store; overwrites attb region)
    gemm_tn<64><<<dim3(48,20), 256, 0, stream>>>(xemb, WT_word, 3072, 512,
                                                 b_word, b_h, imgg, 20, wgb, nullptr, 0, 3072, 1280, dflag, 1);

    hipMemsetAsync(hb0, 0, (size_t)64*512*2, stream);
    hipMemsetAsync(cst, 0, (size_t)64*512*4, stream);

    // sequential recurrence, per-step launches; 256 blocks x 192 thr each
    for (int t = 0; t < 20; ++t){
        const u16* hin = (t & 1) ? hb1 : hb0;
        u16* hout      = (t & 1) ? hb0 : hb1;
        lstm_step<<<256, 192, 0, stream>>>(hin, WT_h, wgb, cst, hout, sent_all, hy_all, t);
    }

    // post-recurrence, z-batched pairs
    GP2 pa{};
    pa.g[0] = { sent_all, WT_sl, b_sl, slf, slb, 1 };
    pa.g[1] = { hy_all,   WT_hl, b_hl, hlf, hlb, 2 };
    gemm_tn2<<<dim3(8,20,2), 256, 0, stream>>>(pa, 512, 512, 512, 1280, dflag);
    GP2 pb{};
    pb.g[0] = { slb, WT_se, b_se, nullptr, sembb, 0 };
    pb.g[1] = { hlb, WT_he, b_he, hemb, nullptr, 0 };
    gemm_tn2<<<dim3(8,20,2), 256, 0, stream>>>(pb, 512, 512, 512, 1280, dflag);

    // attention: high-occupancy score pass, then softmax+ctx pass
    attn_score<<<dim3(1280,4), 256, 0, stream>>>(sembb, hemb, p_att, W_al, b_al, evg, dflag);
    attn_ctx<<<1280, 256, 0, stream>>>(evg, slf, hlf, af, ctx);

    gemm_tn<64><<<dim3(8,20), 256, 0, stream>>>(ctx, WT_a2h, 512, 512,
                                                b_a2h, nullptr, nullptr, 1, nullptr, a2hb, 2, 512, 1280, dflag, 0);
    gemm_tn<128><<<dim3(122,10), 256, 0, stream>>>(a2hb, WT_log, 7808, 512,
                                                   b_log, nullptr, nullptr, 1, nullptr, logits, 0, 7800, 1280, dflag, 0);
    logsoftmax_kernel<<<1280, 256, 0, stream>>>(logits, d_out, dflag);
}

// Round 16
// 397.690 us; speedup vs baseline: 1.0647x; 1.0298x over previous
//
#include <hip/hip_runtime.h>

using short8 = __attribute__((ext_vector_type(8))) short;
using f32x4  = __attribute__((ext_vector_type(4))) float;
typedef unsigned short u16;
typedef unsigned int u32;

__device__ __forceinline__ float b2f(u16 u){
    return __uint_as_float(((u32)u) << 16);
}
__device__ __forceinline__ u16 f2b(float f){
    u32 x = __float_as_uint(f);
    u32 r = (x + 0x7FFFu + ((x >> 16) & 1u)) >> 16;
    return (u16)r;
}
__device__ __forceinline__ float ldx(const void* p, size_t i, bool f32){
    return f32 ? ((const float*)p)[i] : b2f(((const u16*)p)[i]);
}
__device__ __forceinline__ float sigf(float x){
    return __builtin_amdgcn_rcpf(1.0f + __expf(-x));
}
__device__ __forceinline__ float tanhf_(float x){
    float e = __expf(2.0f*x);
    return 1.0f - 2.0f*__builtin_amdgcn_rcpf(e + 1.0f);
}

#define GLDS(g, l) __builtin_amdgcn_global_load_lds((const __attribute__((address_space(1))) void*)(g), \
                        (__attribute__((address_space(3))) void*)(l), 16, 0, 0)

// ---------------- dtype probe ----------------
__global__ void probe_dtype(const void* w, int* flag){
    const u16* up = (const u16*)w;
    int lane = threadIdx.x & 63;
    int cnt = 0;
    for (int i = lane; i < 256; i += 64){
        u16 u = up[2*i];
        int e = (u >> 7) & 0xFF;
        if (e >= 100 && e <= 126) cnt++;
    }
    #pragma unroll
    for (int off = 32; off; off >>= 1) cnt += __shfl_xor(cnt, off);
    if (lane == 0) *flag = (cnt >= 192) ? 0 : 1;   // 1 == inputs are f32
}

// ---------------- fused prep: 11 weight transposes + embedding gather + att convert ----------------
// block ranges: [0,1536) six 512x512 transposes; [1536,6144) three 512x3072; [6144,7168) W_ae;
// [7168,11072) W_log; [11072,13632) gather_emb; [13632,26176) convert_att.
struct PREP {
    const void* tsrc[11]; u16* tdst[11];
    const int* seq; const void* embed; u16* xemb;
    const void* att; u16* attb;
};
__global__ __launch_bounds__(256) void prep_all(PREP pp, const int* __restrict__ dflag){
    __shared__ u16 tile[32][33];
    bool f32 = (*dflag != 0);
    int blk = blockIdx.x;
    int tid = threadIdx.x;
    if (blk < 11072){
        int z, bx, by, K, N, Npad;
        if (blk < 1536){ z = blk >> 8; int idx = blk & 255; bx = idx & 15; by = idx >> 4; K=512; N=512; Npad=512; }
        else if (blk < 6144){ int rel = blk - 1536; z = 6 + rel/1536; int idx = rel%1536; bx = idx%96; by = idx/96; K=512; N=3072; Npad=3072; }
        else if (blk < 7168){ int rel = blk - 6144; z = 9; bx = rel & 15; by = rel >> 4; K=2048; N=512; Npad=512; }
        else { int rel = blk - 7168; z = 10; bx = rel % 244; by = rel / 244; K=512; N=7800; Npad=7808; }
        const void* in = pp.tsrc[z];
        u16* out = pp.tdst[z];
        int tx = tid & 31, ty = tid >> 5;   // (32,8)
        int n = bx*32 + tx;
        #pragma unroll
        for (int i = 0; i < 32; i += 8){
            int k = by*32 + ty + i;
            u16 v = 0;
            if (n < N && k < K)
                v = f32 ? f2b(((const float*)in)[(size_t)k*N + n]) : ((const u16*)in)[(size_t)k*N + n];
            tile[ty+i][tx] = v;
        }
        __syncthreads();
        int k2 = by*32 + tx;
        #pragma unroll
        for (int i = 0; i < 32; i += 8){
            int n2 = bx*32 + ty + i;
            if (n2 < Npad && k2 < K) out[(size_t)n2*K + k2] = tile[tx][ty+i];
        }
    } else if (blk < 13632){
        int idx = (blk - 11072)*256 + tid;
        if (idx < 1280*512){
            int row = idx >> 9, r = idx & 511;
            int b = row / 20, t = row % 20;
            int w = pp.seq[b*21 + t];
            float v = ldx(pp.embed, (size_t)w*512 + r, f32);
            pp.xemb[idx] = f2b(fmaxf(v, 0.f));
        }
    } else {
        int i = (blk - 13632)*256 + tid;
        if (i < 12544*2048/8){
            size_t e = (size_t)i*8;
            if (f32){
                const float4* p = (const float4*)((const float*)pp.att + e);
                float4 v0 = p[0], v1 = p[1];
                u16 o[8] = { f2b(v0.x),f2b(v0.y),f2b(v0.z),f2b(v0.w),
                             f2b(v1.x),f2b(v1.y),f2b(v1.z),f2b(v1.w) };
                *(uint4*)(pp.attb + e) = *(const uint4*)o;
            } else {
                *(uint4*)(pp.attb + e) = *(const uint4*)((const u16*)pp.att + e);
            }
        }
    }
}

// ---------------- mean over A of af -> bf16 ----------------
__global__ __launch_bounds__(256) void mean_af_kernel(const u16* __restrict__ af, u16* __restrict__ mean_af){
    int b = blockIdx.x, tid = threadIdx.x;
    for (int r = tid; r < 512; r += 256){
        float s = 0.f;
        for (int a = 0; a < 196; ++a) s += b2f(af[((size_t)(b*196+a))*512 + r]);
        mean_af[b*512+r] = f2b(s * (1.0f/196.0f));
    }
}

// ---------------- MFMA GEMM: A(M,K) bf16, BT(Npad,K) bf16; tile TM x 64, BK=64 ----------------
// perm: if 1, C index remapped for wgb: row b*20+t -> t*64+b, col gate*512+r -> r*6+gate
template<int TM>
__global__ __launch_bounds__(256) void gemm_tn(const u16* __restrict__ A, const u16* __restrict__ BT,
                                               int N, int K,
                                               const void* __restrict__ bias1, const void* __restrict__ bias2,
                                               const float* __restrict__ rowAdd, int rowDiv,
                                               float* __restrict__ Cf, u16* __restrict__ Cb,
                                               int act, int Nvalid, int Mvalid,
                                               const int* __restrict__ dflag, int perm){
    constexpr int MW = TM/64;
    __shared__ u16 As[TM*64];
    __shared__ u16 Bs[64*64];
    bool f32 = (*dflag != 0);
    int tid = threadIdx.x, lane = tid & 63, w = tid >> 6;
    int lr = lane & 15, kq = lane >> 4;

    int gN = gridDim.x;
    int nwg = gN * gridDim.y;
    int flat = blockIdx.y*gN + blockIdx.x;
    int q = nwg >> 3, r = nwg & 7;
    int xcd = flat & 7, pos = flat >> 3;
    int wgid = (xcd < r ? xcd*(q+1) : r*(q+1) + (xcd-r)*q) + pos;
    int bm = wgid / gN, bn = wgid % gN;
    int row0 = bm*TM, col0 = bn*64;

    f32x4 acc[MW][4];
    #pragma unroll
    for (int m=0;m<MW;++m)
        #pragma unroll
        for (int n=0;n<4;++n) acc[m][n] = (f32x4){0.f,0.f,0.f,0.f};

    for (int k0 = 0; k0 < K; k0 += 64){
        #pragma unroll
        for (int i=0;i<TM/32;++i){
            int c = i*256 + tid;
            int row = c>>3, slot = (c&7) ^ (row&7);
            GLDS((const char*)A + ((size_t)(row0+row)*K + k0)*2 + slot*16,
                 As + (size_t)(i*256 + w*64)*8);
        }
        #pragma unroll
        for (int i=0;i<2;++i){
            int c = i*256 + tid;
            int row = c>>3, slot = (c&7) ^ (row&7);
            GLDS((const char*)BT + ((size_t)(col0+row)*K + k0)*2 + slot*16,
                 Bs + (size_t)(i*256 + w*64)*8);
        }
        __syncthreads();
        short8 av[MW][2], bv[4][2];
        #pragma unroll
        for (int ks=0;ks<2;++ks){
            #pragma unroll
            for (int m=0;m<MW;++m){
                int rrow = w*(TM/4) + m*16 + lr;
                int sl = (ks*4+kq) ^ (rrow&7);
                av[m][ks] = *(const short8*)(As + rrow*64 + sl*8);
            }
            #pragma unroll
            for (int n=0;n<4;++n){
                int rrow = n*16 + lr;
                int sl = (ks*4+kq) ^ (rrow&7);
                bv[n][ks] = *(const short8*)(Bs + rrow*64 + sl*8);
            }
        }
        #pragma unroll
        for (int ks=0;ks<2;++ks)
            #pragma unroll
            for (int m=0;m<MW;++m)
                #pragma unroll
                for (int n=0;n<4;++n)
                    acc[m][n] = __builtin_amdgcn_mfma_f32_16x16x32_bf16(av[m][ks], bv[n][ks], acc[m][n], 0,0,0);
        __syncthreads();
    }

    #pragma unroll
    for (int n=0;n<4;++n){
        int col = col0 + n*16 + lr;
        float bvv = 0.f;
        if (col < Nvalid){
            if (bias1) bvv += ldx(bias1, col, f32);
            if (bias2) bvv += ldx(bias2, col, f32);
        }
        #pragma unroll
        for (int m=0;m<MW;++m){
            #pragma unroll
            for (int rr=0;rr<4;++rr){
                int row = row0 + w*(TM/4) + m*16 + kq*4 + rr;
                if (row < Mvalid && col < Nvalid){
                    float v = acc[m][n][rr] + bvv;
                    if (rowAdd) v += rowAdd[(size_t)(row/rowDiv)*N + col];
                    if (act == 1) v = fmaxf(v, 0.f);
                    else if (act == 2) v = tanhf_(v);
                    size_t o;
                    if (perm){
                        int orow = (row % 20)*64 + row/20;
                        int ocol = (col & 511)*6 + (col >> 9);
                        o = (size_t)orow*N + ocol;
                    } else {
                        o = (size_t)row*N + col;
                    }
                    if (Cf) Cf[o] = v;
                    if (Cb) Cb[o] = f2b(v);
                }
            }
        }
    }
}

// ---------------- z-batched pair of 512x512 GEMMs (M=1280), TM=64 ----------------
struct GP { const u16* A; const u16* BT; const void* b1; float* Cf; u16* Cb; int act; };
struct GP2 { GP g[2]; };
__global__ __launch_bounds__(256) void gemm_tn2(GP2 ps, int N, int K, int Nvalid, int Mvalid,
                                                const int* __restrict__ dflag){
    __shared__ u16 As[64*64];
    __shared__ u16 Bs[64*64];
    bool f32 = (*dflag != 0);
    GP gp = ps.g[blockIdx.z];
    int tid = threadIdx.x, lane = tid & 63, w = tid >> 6;
    int lr = lane & 15, kq = lane >> 4;

    int gN = gridDim.x;
    int nwg = gN * gridDim.y;
    int flat = blockIdx.y*gN + blockIdx.x;
    int q = nwg >> 3, r = nwg & 7;
    int xcd = flat & 7, pos = flat >> 3;
    int wgid = (xcd < r ? xcd*(q+1) : r*(q+1) + (xcd-r)*q) + pos;
    int bm = wgid / gN, bn = wgid % gN;
    int row0 = bm*64, col0 = bn*64;

    f32x4 acc[4];
    #pragma unroll
    for (int n=0;n<4;++n) acc[n] = (f32x4){0.f,0.f,0.f,0.f};

    for (int k0 = 0; k0 < K; k0 += 64){
        {
            int c = tid;
            int row = c>>3, slot = (c&7) ^ (row&7);
            GLDS((const char*)gp.A + ((size_t)(row0+row)*K + k0)*2 + slot*16,
                 As + (size_t)(w*64)*8);
            c = 256 + tid;
            row = c>>3; slot = (c&7) ^ (row&7);
            GLDS((const char*)gp.A + ((size_t)(row0+row)*K + k0)*2 + slot*16,
                 As + (size_t)(256 + w*64)*8);
            c = tid;
            row = c>>3; slot = (c&7) ^ (row&7);
            GLDS((const char*)gp.BT + ((size_t)(col0+row)*K + k0)*2 + slot*16,
                 Bs + (size_t)(w*64)*8);
            c = 256 + tid;
            row = c>>3; slot = (c&7) ^ (row&7);
            GLDS((const char*)gp.BT + ((size_t)(col0+row)*K + k0)*2 + slot*16,
                 Bs + (size_t)(256 + w*64)*8);
        }
        __syncthreads();
        short8 av[2], bv[4][2];
        #pragma unroll
        for (int ks=0;ks<2;++ks){
            int rrow = w*16 + lr;
            int sl = (ks*4+kq) ^ (rrow&7);
            av[ks] = *(const short8*)(As + rrow*64 + sl*8);
            #pragma unroll
            for (int n=0;n<4;++n){
                int rr2 = n*16 + lr;
                int sl2 = (ks*4+kq) ^ (rr2&7);
                bv[n][ks] = *(const short8*)(Bs + rr2*64 + sl2*8);
            }
        }
        #pragma unroll
        for (int ks=0;ks<2;++ks)
            #pragma unroll
            for (int n=0;n<4;++n)
                acc[n] = __builtin_amdgcn_mfma_f32_16x16x32_bf16(av[ks], bv[n][ks], acc[n], 0,0,0);
        __syncthreads();
    }

    #pragma unroll
    for (int n=0;n<4;++n){
        int col = col0 + n*16 + lr;
        float bvv = (col < Nvalid && gp.b1) ? ldx(gp.b1, col, f32) : 0.f;
        #pragma unroll
        for (int rr=0;rr<4;++rr){
            int row = row0 + w*16 + kq*4 + rr;
            if (row < Mvalid && col < Nvalid){
                float v = acc[n][rr] + bvv;
                if (gp.act == 1) v = fmaxf(v, 0.f);
                else if (gp.act == 2) v = tanhf_(v);
                size_t o = (size_t)row*N + col;
                if (gp.Cf) gp.Cf[o] = v;
                if (gp.Cb) gp.Cb[o] = f2b(v);
            }
        }
    }
}

// ---------------- LSTM step v3: 256 blocks x 192 thr; wgb in [t][b][r][6] layout ----------------
#define GP3 52
__global__ __launch_bounds__(192) void lstm_step(const u16* __restrict__ h_in, const u16* __restrict__ WT_h,
                                                 const float* __restrict__ wgb, float* __restrict__ cstate,
                                                 u16* __restrict__ h_out, u16* __restrict__ sent_all,
                                                 u16* __restrict__ hy_all, int t){
    __shared__ float gates[16*GP3];
    int tid = threadIdx.x, lane = tid & 63, w = tid >> 6;   // w in 0..2
    int mg = blockIdx.x >> 6, rg = blockIdx.x & 63;
    int b0 = mg*16, r0 = rg*8;
    int lr = lane & 15, kq = lane >> 4, kg = kq*8;
    int c = w*16 + lr;                    // block col 0..47 = gate*8 + (r-r0)
    int gate = c >> 3, rcol = r0 + (c & 7);
    const u16* Ap = h_in + (size_t)(b0 + lr)*512 + kg;
    const u16* Bp = WT_h + ((size_t)gate*512 + rcol)*512 + kg;
    f32x4 acc = (f32x4){0.f,0.f,0.f,0.f};
    #pragma unroll
    for (int k0 = 0; k0 < 512; k0 += 32){
        short8 a  = *(const short8*)(Ap + k0);
        short8 bf = *(const short8*)(Bp + k0);
        acc = __builtin_amdgcn_mfma_f32_16x16x32_bf16(a, bf, acc, 0,0,0);
    }
    #pragma unroll
    for (int rr = 0; rr < 4; ++rr)
        gates[(kq*4+rr)*GP3 + c] = acc[rr];
    __syncthreads();
    if (tid < 128){
        int ri = tid >> 3, rr = tid & 7;
        int b = b0 + ri, r = r0 + rr;
        const float* wp = wgb + (((size_t)t*64 + b)*512 + r)*6;
        float2 w01 = *(const float2*)(wp);
        float2 w23 = *(const float2*)(wp + 2);
        float2 w45 = *(const float2*)(wp + 4);
        float g0 = gates[ri*GP3 +      rr] + w01.x;
        float g1 = gates[ri*GP3 +  8 + rr] + w01.y;
        float g2 = gates[ri*GP3 + 16 + rr] + w23.x;
        float g3 = gates[ri*GP3 + 24 + rr] + w23.y;
        float g4 = gates[ri*GP3 + 32 + rr] + w45.x;
        float g5 = gates[ri*GP3 + 40 + rr] + w45.y;
        float ig = sigf(g0), fg = sigf(g1), og = sigf(g2), sg = sigf(g3);
        float cell = fmaxf(g4, g5);
        float co = cstate[b*512 + r];
        float cy = tanhf_(fg*co + ig*cell);
        cstate[b*512 + r] = cy;
        float sent = sg*cy, hy = og*cy;
        h_out[(size_t)b*512 + r] = f2b(hy);
        size_t rgl = (size_t)b*20 + t;
        sent_all[rgl*512 + r] = f2b(sent);
        hy_all[rgl*512 + r]   = f2b(hy);
    }
}

// ---------------- attention scores: grid (1280, 4); chunk c handles a ≡ c (mod 4) ----------------
__global__ __launch_bounds__(256) void attn_score(const u16* __restrict__ sembb, const float* __restrict__ h_emb,
                                                  const u16* __restrict__ p_att,
                                                  const void* __restrict__ W_al, const void* __restrict__ b_al,
                                                  float* __restrict__ evg, const int* __restrict__ dflag){
    __shared__ float he_s[512];
    __shared__ float wal_s[512];
    bool f32 = (*dflag != 0);
    int flat = blockIdx.x;
    int row = (flat & 7)*160 + (flat >> 3);   // XCD-clustered rows (1280 = 8*160)
    int b = row / 20;
    int chunk = blockIdx.y;
    int tid = threadIdx.x, lane = tid & 63, w = tid >> 6;
    for (int d = tid; d < 512; d += 256){
        int ad = ((d & 7) >> 1)*128 + (d >> 3)*2 + (d & 1);
        he_s[ad]  = h_emb[(size_t)row*512 + d];
        wal_s[ad] = ldx(W_al, d, f32);
    }
    __syncthreads();
    float bal = ldx(b_al, 0, f32);
    float* evr = evg + (size_t)row*256;

    for (int j = w; chunk + 4*j < 197; j += 8){
        int a0i = chunk + 4*j;
        int a1i = a0i + 16;
        bool has2 = (a1i < 197);
        const u16* r0 = (a0i == 0) ? (sembb + (size_t)row*512)
                                   : (p_att + ((size_t)(b*196 + a0i-1))*512);
        const u16* r1 = has2 ? (p_att + ((size_t)(b*196 + a1i-1))*512) : r0;
        short8 v0 = *(const short8*)(r0 + lane*8);
        short8 v1 = *(const short8*)(r1 + lane*8);
        const u32* pk0 = (const u32*)&v0;
        const u32* pk1 = (const u32*)&v1;
        float p0 = 0.f, p1 = 0.f;
        #pragma unroll
        for (int jp = 0; jp < 4; ++jp){
            float2 he2 = *(const float2*)&he_s[jp*128 + lane*2];
            float2 wa2 = *(const float2*)&wal_s[jp*128 + lane*2];
            u32 u0 = pk0[jp], u1 = pk1[jp];
            float x00 = __uint_as_float(u0 << 16)          + he2.x;
            float x01 = __uint_as_float(u0 & 0xFFFF0000u)  + he2.y;
            float x10 = __uint_as_float(u1 << 16)          + he2.x;
            float x11 = __uint_as_float(u1 & 0xFFFF0000u)  + he2.y;
            p0 += tanhf_(x00)*wa2.x;
            p0 += tanhf_(x01)*wa2.y;
            p1 += tanhf_(x10)*wa2.x;
            p1 += tanhf_(x11)*wa2.y;
        }
        #pragma unroll
        for (int off = 32; off; off >>= 1){
            p0 += __shfl_xor(p0, off);
            p1 += __shfl_xor(p1, off);
        }
        if (lane == 0){
            evr[a0i] = p0 + bal;
            if (has2) evr[a1i] = p1 + bal;
        }
    }
}

// ---------------- attention ctx: softmax over 197 + cHat + h_lin -> ctx ----------------
__global__ __launch_bounds__(256) void attn_ctx(const float* __restrict__ evg,
                                                const float* __restrict__ sent_lin_f, const float* __restrict__ h_lin_f,
                                                const u16* __restrict__ af,
                                                u16* __restrict__ ctx_in){
    __shared__ float ev[208];
    __shared__ float red2[2];
    int flat = blockIdx.x;
    int row = (flat & 7)*160 + (flat >> 3);
    int b = row / 20;
    int tid = threadIdx.x, lane = tid & 63, w = tid >> 6;
    const float* evr = evg + (size_t)row*256;
    for (int a = tid; a < 197; a += 256) ev[a] = evr[a];
    __syncthreads();
    if (w == 0){
        float m = -1e30f;
        for (int a = lane; a < 197; a += 64) m = fmaxf(m, ev[a]);
        #pragma unroll
        for (int off = 32; off; off >>= 1) m = fmaxf(m, __shfl_xor(m, off));
        float s = 0.f;
        for (int a = lane; a < 197; a += 64) s += __expf(ev[a] - m);
        #pragma unroll
        for (int off = 32; off; off >>= 1) s += __shfl_xor(s, off);
        if (lane == 0){ red2[0] = m; red2[1] = __builtin_amdgcn_rcpf(s); }
    }
    __syncthreads();
    float m = red2[0], inv = red2[1];
    for (int a = tid; a < 197; a += 256) ev[a] = __expf(ev[a] - m) * inv;
    __syncthreads();

    int d = tid*2;
    const u16* afb = af + (size_t)b*196*512 + d;
    float s0 = 0.f, s1 = 0.f, t0 = 0.f, t1 = 0.f;
    for (int a = 0; a < 196; a += 2){
        float e0 = ev[a+1], e1 = ev[a+2];
        u32 u0 = *(const u32*)(afb + (size_t)a*512);
        u32 u1 = *(const u32*)(afb + (size_t)(a+1)*512);
        s0 += e0 * __uint_as_float(u0 << 16);
        s1 += e0 * __uint_as_float(u0 & 0xFFFF0000u);
        t0 += e1 * __uint_as_float(u1 << 16);
        t1 += e1 * __uint_as_float(u1 & 0xFFFF0000u);
    }
    float e00 = ev[0];
    float a0 = e00*sent_lin_f[(size_t)row*512 + d]     + s0 + t0 + h_lin_f[(size_t)row*512 + d];
    float a1 = e00*sent_lin_f[(size_t)row*512 + d + 1] + s1 + t1 + h_lin_f[(size_t)row*512 + d + 1];
    ctx_in[(size_t)row*512 + d]     = f2b(a0);
    ctx_in[(size_t)row*512 + d + 1] = f2b(a1);
}

// ---------------- row log-softmax over 7800: single global read, row cached in regs ----------------
__global__ __launch_bounds__(256) void logsoftmax_kernel(const u16* __restrict__ logits, void* __restrict__ out,
                                                         const int* __restrict__ dflag){
    __shared__ float red[256];
    bool f32 = (*dflag != 0);
    int row = blockIdx.x, tid = threadIdx.x;
    const u16* lp = logits + (size_t)row*7808;
    float xs[31];
    float m = -1e30f;
    #pragma unroll
    for (int k = 0; k < 31; ++k){
        int v = k*256 + tid;
        xs[k] = (v < 7800) ? b2f(lp[v]) : -1e30f;
        m = fmaxf(m, xs[k]);
    }
    red[tid] = m; __syncthreads();
    for (int s = 128; s; s >>= 1){ if (tid < s) red[tid] = fmaxf(red[tid], red[tid+s]); __syncthreads(); }
    m = red[0]; __syncthreads();
    float s = 0.f;
    #pragma unroll
    for (int k = 0; k < 31; ++k) s += __expf(xs[k] - m);
    red[tid] = s; __syncthreads();
    for (int st = 128; st; st >>= 1){ if (tid < st) red[tid] += red[tid+st]; __syncthreads(); }
    float lse = m + __logf(red[0]);
    if (f32){
        float* op = (float*)out + (size_t)row*7800;
        #pragma unroll
        for (int k = 0; k < 31; ++k){
            int v = k*256 + tid;
            if (v < 7800) op[v] = xs[k] - lse;
        }
    } else {
        u16* op = (u16*)out + (size_t)row*7800;
        #pragma unroll
        for (int k = 0; k < 31; ++k){
            int v = k*256 + tid;
            if (v < 7800) op[v] = f2b(xs[k] - lse);
        }
    }
}

extern "C" void kernel_launch(void* const* d_in, const int* in_sizes, int n_in,
                              void* d_out, int out_size, void* d_ws, size_t ws_size,
                              hipStream_t stream){
    (void)in_sizes; (void)n_in; (void)out_size; (void)ws_size;
    const int* seq    = (const int*)d_in[0];
    const void* att   = d_in[1];
    const void* embed = d_in[2];
    const void* W_word= d_in[3];  const void* b_word = d_in[4];
    const void* W_h   = d_in[5];  const void* b_h    = d_in[6];
    const void* W_img = d_in[7];  const void* b_img  = d_in[8];
    const void* W_ae  = d_in[9];  const void* b_ae   = d_in[10];
    const void* W_c2a = d_in[11]; const void* b_c2a  = d_in[12];
    const void* W_sl  = d_in[13]; const void* b_sl   = d_in[14];
    const void* W_se  = d_in[15]; const void* b_se   = d_in[16];
    const void* W_hl  = d_in[17]; const void* b_hl   = d_in[18];
    const void* W_he  = d_in[19]; const void* b_he   = d_in[20];
    const void* W_al  = d_in[21]; const void* b_al   = d_in[22];
    const void* W_a2h = d_in[23]; const void* b_a2h  = d_in[24];
    const void* W_log = d_in[25]; const void* b_log  = d_in[26];

    char* p = (char*)d_ws;
    auto alloc = [&](size_t bytes)->char*{ char* r = p; p += (bytes + 255) & ~(size_t)255; return r; };

    int* dflag   = (int*)alloc(256);
    u16* WT_ae   = (u16*)alloc((size_t)512*2048*2);
    u16* WT_word = (u16*)alloc((size_t)3072*512*2);
    u16* WT_h    = (u16*)alloc((size_t)3072*512*2);
    u16* WT_img  = (u16*)alloc((size_t)3072*512*2);
    u16* WT_c2a  = (u16*)alloc((size_t)512*512*2);
    u16* WT_sl   = (u16*)alloc((size_t)512*512*2);
    u16* WT_se   = (u16*)alloc((size_t)512*512*2);
    u16* WT_hl   = (u16*)alloc((size_t)512*512*2);
    u16* WT_he   = (u16*)alloc((size_t)512*512*2);
    u16* WT_a2h  = (u16*)alloc((size_t)512*512*2);
    u16* WT_log  = (u16*)alloc((size_t)7808*512*2);
    u16* af      = (u16*)alloc((size_t)12544*512*2);
    u16* p_att   = (u16*)alloc((size_t)12544*512*2);
    u16* meanb   = (u16*)alloc((size_t)64*512*2);
    float* imgg  = (float*)alloc((size_t)64*3072*4);
    u16* xemb    = (u16*)alloc((size_t)1280*512*2);
    float* wgb   = (float*)alloc((size_t)1280*3072*4);   // [t][b][512][6] layout
    u16* hb0     = (u16*)alloc((size_t)64*512*2);
    u16* hb1     = (u16*)alloc((size_t)64*512*2);
    float* cst   = (float*)alloc((size_t)64*512*4);
    u16* sent_all= (u16*)alloc((size_t)1280*512*2);
    u16* hy_all  = (u16*)alloc((size_t)1280*512*2);
    float* slf   = (float*)alloc((size_t)1280*512*4);
    u16* slb     = (u16*)alloc((size_t)1280*512*2);
    float* hlf   = (float*)alloc((size_t)1280*512*4);
    u16* hlb     = (u16*)alloc((size_t)1280*512*2);
    u16* sembb   = (u16*)alloc((size_t)1280*512*2);
    float* hemb  = (float*)alloc((size_t)1280*512*4);
    u16* ctx     = (u16*)alloc((size_t)1280*512*2);
    u16* a2hb    = (u16*)alloc((size_t)1280*512*2);
    float* evg   = (float*)alloc((size_t)1280*256*4);
    u16* logits  = (u16*)alloc((size_t)1280*7808*2);

    // attb (51.4MB) aliases late-lifetime region [wgb .. logits]:
    // written by prep_all, consumed only by af GEMM, dead before wgb is written.
    u16* attb = (u16*)wgb;

    probe_dtype<<<1, 64, 0, stream>>>(W_ae, dflag);

    {
        PREP pp{};
        pp.tsrc[0]=W_c2a; pp.tdst[0]=WT_c2a;
        pp.tsrc[1]=W_sl;  pp.tdst[1]=WT_sl;
        pp.tsrc[2]=W_se;  pp.tdst[2]=WT_se;
        pp.tsrc[3]=W_hl;  pp.tdst[3]=WT_hl;
        pp.tsrc[4]=W_he;  pp.tdst[4]=WT_he;
        pp.tsrc[5]=W_a2h; pp.tdst[5]=WT_a2h;
        pp.tsrc[6]=W_word;pp.tdst[6]=WT_word;
        pp.tsrc[7]=W_h;   pp.tdst[7]=WT_h;
        pp.tsrc[8]=W_img; pp.tdst[8]=WT_img;
        pp.tsrc[9]=W_ae;  pp.tdst[9]=WT_ae;
        pp.tsrc[10]=W_log;pp.tdst[10]=WT_log;
        pp.seq = seq; pp.embed = embed; pp.xemb = xemb;
        pp.att = att; pp.attb = attb;
        prep_all<<<26176, 256, 0, stream>>>(pp, dflag);
    }

    hipMemsetAsync(hb0, 0, (size_t)64*512*2, stream);
    hipMemsetAsync(cst, 0, (size_t)64*512*4, stream);

    // af = relu(att @ W_ae + b_ae)  -- TM=64, 1568 blocks
    gemm_tn<64><<<dim3(8,196), 256, 0, stream>>>(attb, WT_ae, 512, 2048,
                                                 b_ae, nullptr, nullptr, 1, nullptr, af, 1, 512, 12544, dflag, 0);
    // p_att = af @ W_c2a + b_c2a  -- TM=64
    gemm_tn<64><<<dim3(8,196), 256, 0, stream>>>(af, WT_c2a, 512, 512,
                                                 b_c2a, nullptr, nullptr, 1, nullptr, p_att, 0, 512, 12544, dflag, 0);
    mean_af_kernel<<<64, 256, 0, stream>>>(af, meanb);
    gemm_tn<64><<<dim3(48,1), 256, 0, stream>>>(meanb, WT_img, 3072, 512,
                                                b_img, nullptr, nullptr, 1, imgg, nullptr, 0, 3072, 64, dflag, 0);
    // wgb[t][b][r][6] = x_emb @ W_word + b_word + b_h + img_gate[b]   (perm store; overwrites attb region)
    gemm_tn<64><<<dim3(48,20), 256, 0, stream>>>(xemb, WT_word, 3072, 512,
                                                 b_word, b_h, imgg, 20, wgb, nullptr, 0, 3072, 1280, dflag, 1);

    // sequential recurrence, per-step launches; 256 blocks x 192 thr each
    for (int t = 0; t < 20; ++t){
        const u16* hin = (t & 1) ? hb1 : hb0;
        u16* hout      = (t & 1) ? hb0 : hb1;
        lstm_step<<<256, 192, 0, stream>>>(hin, WT_h, wgb, cst, hout, sent_all, hy_all, t);
    }

    // post-recurrence, z-batched pairs
    GP2 pa{};
    pa.g[0] = { sent_all, WT_sl, b_sl, slf, slb, 1 };
    pa.g[1] = { hy_all,   WT_hl, b_hl, hlf, hlb, 2 };
    gemm_tn2<<<dim3(8,20,2), 256, 0, stream>>>(pa, 512, 512, 512, 1280, dflag);
    GP2 pb{};
    pb.g[0] = { slb, WT_se, b_se, nullptr, sembb, 0 };
    pb.g[1] = { hlb, WT_he, b_he, hemb, nullptr, 0 };
    gemm_tn2<<<dim3(8,20,2), 256, 0, stream>>>(pb, 512, 512, 512, 1280, dflag);

    // attention: high-occupancy score pass, then softmax+ctx pass
    attn_score<<<dim3(1280,4), 256, 0, stream>>>(sembb, hemb, p_att, W_al, b_al, evg, dflag);
    attn_ctx<<<1280, 256, 0, stream>>>(evg, slf, hlf, af, ctx);

    gemm_tn<64><<<dim3(8,20), 256, 0, stream>>>(ctx, WT_a2h, 512, 512,
                                                b_a2h, nullptr, nullptr, 1, nullptr, a2hb, 2, 512, 1280, dflag, 0);
    gemm_tn<64><<<dim3(122,20), 256, 0, stream>>>(a2hb, WT_log, 7808, 512,
                                                  b_log, nullptr, nullptr, 1, nullptr, logits, 0, 7800, 1280, dflag, 0);
    logsoftmax_kernel<<<1280, 256, 0, stream>>>(logits, d_out, dflag);
}

// Round 17
// 393.176 us; speedup vs baseline: 1.0769x; 1.0115x over previous
//
#include <hip/hip_runtime.h>

using short8 = __attribute__((ext_vector_type(8))) short;
using f32x4  = __attribute__((ext_vector_type(4))) float;
typedef unsigned short u16;
typedef unsigned int u32;

__device__ __forceinline__ float b2f(u16 u){
    return __uint_as_float(((u32)u) << 16);
}
__device__ __forceinline__ u16 f2b(float f){
    u32 x = __float_as_uint(f);
    u32 r = (x + 0x7FFFu + ((x >> 16) & 1u)) >> 16;
    return (u16)r;
}
__device__ __forceinline__ float ldx(const void* p, size_t i, bool f32){
    return f32 ? ((const float*)p)[i] : b2f(((const u16*)p)[i]);
}
__device__ __forceinline__ float sigf(float x){
    return __builtin_amdgcn_rcpf(1.0f + __expf(-x));
}
__device__ __forceinline__ float tanhf_(float x){
    float e = __expf(2.0f*x);
    return 1.0f - 2.0f*__builtin_amdgcn_rcpf(e + 1.0f);
}

#define GLDS(g, l) __builtin_amdgcn_global_load_lds((const __attribute__((address_space(1))) void*)(g), \
                        (__attribute__((address_space(3))) void*)(l), 16, 0, 0)

// ---------------- dtype probe ----------------
__global__ void probe_dtype(const void* w, int* flag){
    const u16* up = (const u16*)w;
    int lane = threadIdx.x & 63;
    int cnt = 0;
    for (int i = lane; i < 256; i += 64){
        u16 u = up[2*i];
        int e = (u >> 7) & 0xFF;
        if (e >= 100 && e <= 126) cnt++;
    }
    #pragma unroll
    for (int off = 32; off; off >>= 1) cnt += __shfl_xor(cnt, off);
    if (lane == 0) *flag = (cnt >= 192) ? 0 : 1;   // 1 == inputs are f32
}

// ---------------- fused prep v2: 64x64-tile transposes + embedding gather + att convert ----------------
// block ranges: [0,384) six 512x512; [384,1536) three 512x3072; [1536,1792) W_ae 2048x512;
// [1792,2768) W_log 512x7800->7808; [2768,5328) gather_emb; [5328,17872) convert_att.
struct PREP {
    const void* tsrc[11]; u16* tdst[11];
    const int* seq; const void* embed; u16* xemb;
    const void* att; u16* attb;
};
__global__ __launch_bounds__(256) void prep_all(PREP pp, const int* __restrict__ dflag){
    __shared__ u16 T[64][66];
    bool f32 = (*dflag != 0);
    int blk = blockIdx.x;
    int tid = threadIdx.x;
    if (blk < 2768){
        int z, bx, by, K, N, Npad;
        if (blk < 384){ z = blk >> 6; int idx = blk & 63; bx = idx & 7; by = idx >> 3; K=512; N=512; Npad=512; }
        else if (blk < 1536){ int rel = blk - 384; z = 6 + rel/384; int idx = rel%384; bx = idx%48; by = idx/48; K=512; N=3072; Npad=3072; }
        else if (blk < 1792){ int rel = blk - 1536; z = 9; bx = rel & 7; by = rel >> 3; K=2048; N=512; Npad=512; }
        else { int rel = blk - 1792; z = 10; bx = rel % 122; by = rel / 122; K=512; N=7800; Npad=7808; }
        const void* in = pp.tsrc[z];
        u16* out = pp.tdst[z];
        int tx = tid & 63, ty = tid >> 6;   // (64,4)
        int n = bx*64 + tx;
        #pragma unroll
        for (int i = 0; i < 64; i += 4){
            int k = by*64 + ty + i;
            u16 v = 0;
            if (n < N && k < K)
                v = f32 ? f2b(((const float*)in)[(size_t)k*N + n]) : ((const u16*)in)[(size_t)k*N + n];
            T[tx][ty + i] = v;              // T[n_local][k_local]
        }
        __syncthreads();
        int k2 = by*64 + tx;
        #pragma unroll
        for (int i = 0; i < 64; i += 4){
            int n2 = bx*64 + ty + i;
            if (n2 < Npad && k2 < K) out[(size_t)n2*K + k2] = T[ty + i][tx];
        }
    } else if (blk < 5328){
        int idx = (blk - 2768)*256 + tid;
        if (idx < 1280*512){
            int row = idx >> 9, r = idx & 511;
            int b = row / 20, t = row % 20;
            int w = pp.seq[b*21 + t];
            float v = ldx(pp.embed, (size_t)w*512 + r, f32);
            pp.xemb[idx] = f2b(fmaxf(v, 0.f));
        }
    } else {
        int i = (blk - 5328)*256 + tid;
        if (i < 12544*2048/8){
            size_t e = (size_t)i*8;
            if (f32){
                const float4* p = (const float4*)((const float*)pp.att + e);
                float4 v0 = p[0], v1 = p[1];
                u16 o[8] = { f2b(v0.x),f2b(v0.y),f2b(v0.z),f2b(v0.w),
                             f2b(v1.x),f2b(v1.y),f2b(v1.z),f2b(v1.w) };
                *(uint4*)(pp.attb + e) = *(const uint4*)o;
            } else {
                *(uint4*)(pp.attb + e) = *(const uint4*)((const u16*)pp.att + e);
            }
        }
    }
}

// ---------------- mean over A of af -> bf16 ----------------
__global__ __launch_bounds__(256) void mean_af_kernel(const u16* __restrict__ af, u16* __restrict__ mean_af){
    int b = blockIdx.x, tid = threadIdx.x;
    for (int r = tid; r < 512; r += 256){
        float s = 0.f;
        for (int a = 0; a < 196; ++a) s += b2f(af[((size_t)(b*196+a))*512 + r]);
        mean_af[b*512+r] = f2b(s * (1.0f/196.0f));
    }
}

// ---------------- MFMA GEMM: A(M,K) bf16, BT(Npad,K) bf16; tile TM x 64, BK=64 ----------------
// perm: if 1, C index remapped for wgb: row b*20+t -> t*64+b, col gate*512+r -> r*6+gate
template<int TM>
__global__ __launch_bounds__(256) void gemm_tn(const u16* __restrict__ A, const u16* __restrict__ BT,
                                               int N, int K,
                                               const void* __restrict__ bias1, const void* __restrict__ bias2,
                                               const float* __restrict__ rowAdd, int rowDiv,
                                               float* __restrict__ Cf, u16* __restrict__ Cb,
                                               int act, int Nvalid, int Mvalid,
                                               const int* __restrict__ dflag, int perm){
    constexpr int MW = TM/64;
    __shared__ u16 As[TM*64];
    __shared__ u16 Bs[64*64];
    bool f32 = (*dflag != 0);
    int tid = threadIdx.x, lane = tid & 63, w = tid >> 6;
    int lr = lane & 15, kq = lane >> 4;

    int gN = gridDim.x;
    int nwg = gN * gridDim.y;
    int flat = blockIdx.y*gN + blockIdx.x;
    int q = nwg >> 3, r = nwg & 7;
    int xcd = flat & 7, pos = flat >> 3;
    int wgid = (xcd < r ? xcd*(q+1) : r*(q+1) + (xcd-r)*q) + pos;
    int bm = wgid / gN, bn = wgid % gN;
    int row0 = bm*TM, col0 = bn*64;

    f32x4 acc[MW][4];
    #pragma unroll
    for (int m=0;m<MW;++m)
        #pragma unroll
        for (int n=0;n<4;++n) acc[m][n] = (f32x4){0.f,0.f,0.f,0.f};

    for (int k0 = 0; k0 < K; k0 += 64){
        #pragma unroll
        for (int i=0;i<TM/32;++i){
            int c = i*256 + tid;
            int row = c>>3, slot = (c&7) ^ (row&7);
            GLDS((const char*)A + ((size_t)(row0+row)*K + k0)*2 + slot*16,
                 As + (size_t)(i*256 + w*64)*8);
        }
        #pragma unroll
        for (int i=0;i<2;++i){
            int c = i*256 + tid;
            int row = c>>3, slot = (c&7) ^ (row&7);
            GLDS((const char*)BT + ((size_t)(col0+row)*K + k0)*2 + slot*16,
                 Bs + (size_t)(i*256 + w*64)*8);
        }
        __syncthreads();
        short8 av[MW][2], bv[4][2];
        #pragma unroll
        for (int ks=0;ks<2;++ks){
            #pragma unroll
            for (int m=0;m<MW;++m){
                int rrow = w*(TM/4) + m*16 + lr;
                int sl = (ks*4+kq) ^ (rrow&7);
                av[m][ks] = *(const short8*)(As + rrow*64 + sl*8);
            }
            #pragma unroll
            for (int n=0;n<4;++n){
                int rrow = n*16 + lr;
                int sl = (ks*4+kq) ^ (rrow&7);
                bv[n][ks] = *(const short8*)(Bs + rrow*64 + sl*8);
            }
        }
        #pragma unroll
        for (int ks=0;ks<2;++ks)
            #pragma unroll
            for (int m=0;m<MW;++m)
                #pragma unroll
                for (int n=0;n<4;++n)
                    acc[m][n] = __builtin_amdgcn_mfma_f32_16x16x32_bf16(av[m][ks], bv[n][ks], acc[m][n], 0,0,0);
        __syncthreads();
    }

    #pragma unroll
    for (int n=0;n<4;++n){
        int col = col0 + n*16 + lr;
        float bvv = 0.f;
        if (col < Nvalid){
            if (bias1) bvv += ldx(bias1, col, f32);
            if (bias2) bvv += ldx(bias2, col, f32);
        }
        #pragma unroll
        for (int m=0;m<MW;++m){
            #pragma unroll
            for (int rr=0;rr<4;++rr){
                int row = row0 + w*(TM/4) + m*16 + kq*4 + rr;
                if (row < Mvalid && col < Nvalid){
                    float v = acc[m][n][rr] + bvv;
                    if (rowAdd) v += rowAdd[(size_t)(row/rowDiv)*N + col];
                    if (act == 1) v = fmaxf(v, 0.f);
                    else if (act == 2) v = tanhf_(v);
                    size_t o;
                    if (perm){
                        int orow = (row % 20)*64 + row/20;
                        int ocol = (col & 511)*6 + (col >> 9);
                        o = (size_t)orow*N + ocol;
                    } else {
                        o = (size_t)row*N + col;
                    }
                    if (Cf) Cf[o] = v;
                    if (Cb) Cb[o] = f2b(v);
                }
            }
        }
    }
}

// ---------------- z-batched pair of 512x512 GEMMs (M=1280), TM=64 ----------------
struct GP { const u16* A; const u16* BT; const void* b1; float* Cf; u16* Cb; int act; };
struct GP2 { GP g[2]; };
__global__ __launch_bounds__(256) void gemm_tn2(GP2 ps, int N, int K, int Nvalid, int Mvalid,
                                                const int* __restrict__ dflag){
    __shared__ u16 As[64*64];
    __shared__ u16 Bs[64*64];
    bool f32 = (*dflag != 0);
    GP gp = ps.g[blockIdx.z];
    int tid = threadIdx.x, lane = tid & 63, w = tid >> 6;
    int lr = lane & 15, kq = lane >> 4;

    int gN = gridDim.x;
    int nwg = gN * gridDim.y;
    int flat = blockIdx.y*gN + blockIdx.x;
    int q = nwg >> 3, r = nwg & 7;
    int xcd = flat & 7, pos = flat >> 3;
    int wgid = (xcd < r ? xcd*(q+1) : r*(q+1) + (xcd-r)*q) + pos;
    int bm = wgid / gN, bn = wgid % gN;
    int row0 = bm*64, col0 = bn*64;

    f32x4 acc[4];
    #pragma unroll
    for (int n=0;n<4;++n) acc[n] = (f32x4){0.f,0.f,0.f,0.f};

    for (int k0 = 0; k0 < K; k0 += 64){
        {
            int c = tid;
            int row = c>>3, slot = (c&7) ^ (row&7);
            GLDS((const char*)gp.A + ((size_t)(row0+row)*K + k0)*2 + slot*16,
                 As + (size_t)(w*64)*8);
            c = 256 + tid;
            row = c>>3; slot = (c&7) ^ (row&7);
            GLDS((const char*)gp.A + ((size_t)(row0+row)*K + k0)*2 + slot*16,
                 As + (size_t)(256 + w*64)*8);
            c = tid;
            row = c>>3; slot = (c&7) ^ (row&7);
            GLDS((const char*)gp.BT + ((size_t)(col0+row)*K + k0)*2 + slot*16,
                 Bs + (size_t)(w*64)*8);
            c = 256 + tid;
            row = c>>3; slot = (c&7) ^ (row&7);
            GLDS((const char*)gp.BT + ((size_t)(col0+row)*K + k0)*2 + slot*16,
                 Bs + (size_t)(256 + w*64)*8);
        }
        __syncthreads();
        short8 av[2], bv[4][2];
        #pragma unroll
        for (int ks=0;ks<2;++ks){
            int rrow = w*16 + lr;
            int sl = (ks*4+kq) ^ (rrow&7);
            av[ks] = *(const short8*)(As + rrow*64 + sl*8);
            #pragma unroll
            for (int n=0;n<4;++n){
                int rr2 = n*16 + lr;
                int sl2 = (ks*4+kq) ^ (rr2&7);
                bv[n][ks] = *(const short8*)(Bs + rr2*64 + sl2*8);
            }
        }
        #pragma unroll
        for (int ks=0;ks<2;++ks)
            #pragma unroll
            for (int n=0;n<4;++n)
                acc[n] = __builtin_amdgcn_mfma_f32_16x16x32_bf16(av[ks], bv[n][ks], acc[n], 0,0,0);
        __syncthreads();
    }

    #pragma unroll
    for (int n=0;n<4;++n){
        int col = col0 + n*16 + lr;
        float bvv = (col < Nvalid && gp.b1) ? ldx(gp.b1, col, f32) : 0.f;
        #pragma unroll
        for (int rr=0;rr<4;++rr){
            int row = row0 + w*16 + kq*4 + rr;
            if (row < Mvalid && col < Nvalid){
                float v = acc[n][rr] + bvv;
                if (gp.act == 1) v = fmaxf(v, 0.f);
                else if (gp.act == 2) v = tanhf_(v);
                size_t o = (size_t)row*N + col;
                if (gp.Cf) gp.Cf[o] = v;
                if (gp.Cb) gp.Cb[o] = f2b(v);
            }
        }
    }
}

// ---------------- LSTM step v3: 256 blocks x 192 thr; wgb in [t][b][r][6] layout ----------------
#define GP3 52
__global__ __launch_bounds__(192) void lstm_step(const u16* __restrict__ h_in, const u16* __restrict__ WT_h,
                                                 const float* __restrict__ wgb, float* __restrict__ cstate,
                                                 u16* __restrict__ h_out, u16* __restrict__ sent_all,
                                                 u16* __restrict__ hy_all, int t){
    __shared__ float gates[16*GP3];
    int tid = threadIdx.x, lane = tid & 63, w = tid >> 6;   // w in 0..2
    int mg = blockIdx.x >> 6, rg = blockIdx.x & 63;
    int b0 = mg*16, r0 = rg*8;
    int lr = lane & 15, kq = lane >> 4, kg = kq*8;
    int c = w*16 + lr;                    // block col 0..47 = gate*8 + (r-r0)
    int gate = c >> 3, rcol = r0 + (c & 7);
    const u16* Ap = h_in + (size_t)(b0 + lr)*512 + kg;
    const u16* Bp = WT_h + ((size_t)gate*512 + rcol)*512 + kg;
    f32x4 acc = (f32x4){0.f,0.f,0.f,0.f};
    #pragma unroll
    for (int k0 = 0; k0 < 512; k0 += 32){
        short8 a  = *(const short8*)(Ap + k0);
        short8 bf = *(const short8*)(Bp + k0);
        acc = __builtin_amdgcn_mfma_f32_16x16x32_bf16(a, bf, acc, 0,0,0);
    }
    #pragma unroll
    for (int rr = 0; rr < 4; ++rr)
        gates[(kq*4+rr)*GP3 + c] = acc[rr];
    __syncthreads();
    if (tid < 128){
        int ri = tid >> 3, rr = tid & 7;
        int b = b0 + ri, r = r0 + rr;
        const float* wp = wgb + (((size_t)t*64 + b)*512 + r)*6;
        float2 w01 = *(const float2*)(wp);
        float2 w23 = *(const float2*)(wp + 2);
        float2 w45 = *(const float2*)(wp + 4);
        float g0 = gates[ri*GP3 +      rr] + w01.x;
        float g1 = gates[ri*GP3 +  8 + rr] + w01.y;
        float g2 = gates[ri*GP3 + 16 + rr] + w23.x;
        float g3 = gates[ri*GP3 + 24 + rr] + w23.y;
        float g4 = gates[ri*GP3 + 32 + rr] + w45.x;
        float g5 = gates[ri*GP3 + 40 + rr] + w45.y;
        float ig = sigf(g0), fg = sigf(g1), og = sigf(g2), sg = sigf(g3);
        float cell = fmaxf(g4, g5);
        float co = cstate[b*512 + r];
        float cy = tanhf_(fg*co + ig*cell);
        cstate[b*512 + r] = cy;
        float sent = sg*cy, hy = og*cy;
        h_out[(size_t)b*512 + r] = f2b(hy);
        size_t rgl = (size_t)b*20 + t;
        sent_all[rgl*512 + r] = f2b(sent);
        hy_all[rgl*512 + r]   = f2b(hy);
    }
}

// ---------------- attention scores: grid (1280, 4); chunk c handles a ≡ c (mod 4) ----------------
__global__ __launch_bounds__(256) void attn_score(const u16* __restrict__ sembb, const float* __restrict__ h_emb,
                                                  const u16* __restrict__ p_att,
                                                  const void* __restrict__ W_al, const void* __restrict__ b_al,
                                                  float* __restrict__ evg, const int* __restrict__ dflag){
    __shared__ float he_s[512];
    __shared__ float wal_s[512];
    bool f32 = (*dflag != 0);
    int flat = blockIdx.x;
    int row = (flat & 7)*160 + (flat >> 3);   // XCD-clustered rows (1280 = 8*160)
    int b = row / 20;
    int chunk = blockIdx.y;
    int tid = threadIdx.x, lane = tid & 63, w = tid >> 6;
    for (int d = tid; d < 512; d += 256){
        int ad = ((d & 7) >> 1)*128 + (d >> 3)*2 + (d & 1);
        he_s[ad]  = h_emb[(size_t)row*512 + d];
        wal_s[ad] = ldx(W_al, d, f32);
    }
    __syncthreads();
    float bal = ldx(b_al, 0, f32);
    float* evr = evg + (size_t)row*256;

    for (int j = w; chunk + 4*j < 197; j += 8){
        int a0i = chunk + 4*j;
        int a1i = a0i + 16;
        bool has2 = (a1i < 197);
        const u16* r0 = (a0i == 0) ? (sembb + (size_t)row*512)
                                   : (p_att + ((size_t)(b*196 + a0i-1))*512);
        const u16* r1 = has2 ? (p_att + ((size_t)(b*196 + a1i-1))*512) : r0;
        short8 v0 = *(const short8*)(r0 + lane*8);
        short8 v1 = *(const short8*)(r1 + lane*8);
        const u32* pk0 = (const u32*)&v0;
        const u32* pk1 = (const u32*)&v1;
        float p0 = 0.f, p1 = 0.f;
        #pragma unroll
        for (int jp = 0; jp < 4; ++jp){
            float2 he2 = *(const float2*)&he_s[jp*128 + lane*2];
            float2 wa2 = *(const float2*)&wal_s[jp*128 + lane*2];
            u32 u0 = pk0[jp], u1 = pk1[jp];
            float x00 = __uint_as_float(u0 << 16)          + he2.x;
            float x01 = __uint_as_float(u0 & 0xFFFF0000u)  + he2.y;
            float x10 = __uint_as_float(u1 << 16)          + he2.x;
            float x11 = __uint_as_float(u1 & 0xFFFF0000u)  + he2.y;
            p0 += tanhf_(x00)*wa2.x;
            p0 += tanhf_(x01)*wa2.y;
            p1 += tanhf_(x10)*wa2.x;
            p1 += tanhf_(x11)*wa2.y;
        }
        #pragma unroll
        for (int off = 32; off; off >>= 1){
            p0 += __shfl_xor(p0, off);
            p1 += __shfl_xor(p1, off);
        }
        if (lane == 0){
            evr[a0i] = p0 + bal;
            if (has2) evr[a1i] = p1 + bal;
        }
    }
}

// ---------------- attention ctx: softmax over 197 + cHat + h_lin -> ctx ----------------
__global__ __launch_bounds__(256) void attn_ctx(const float* __restrict__ evg,
                                                const float* __restrict__ sent_lin_f, const float* __restrict__ h_lin_f,
                                                const u16* __restrict__ af,
                                                u16* __restrict__ ctx_in){
    __shared__ float ev[208];
    __shared__ float red2[2];
    int flat = blockIdx.x;
    int row = (flat & 7)*160 + (flat >> 3);
    int b = row / 20;
    int tid = threadIdx.x, lane = tid & 63, w = tid >> 6;
    const float* evr = evg + (size_t)row*256;
    for (int a = tid; a < 197; a += 256) ev[a] = evr[a];
    __syncthreads();
    if (w == 0){
        float m = -1e30f;
        for (int a = lane; a < 197; a += 64) m = fmaxf(m, ev[a]);
        #pragma unroll
        for (int off = 32; off; off >>= 1) m = fmaxf(m, __shfl_xor(m, off));
        float s = 0.f;
        for (int a = lane; a < 197; a += 64) s += __expf(ev[a] - m);
        #pragma unroll
        for (int off = 32; off; off >>= 1) s += __shfl_xor(s, off);
        if (lane == 0){ red2[0] = m; red2[1] = __builtin_amdgcn_rcpf(s); }
    }
    __syncthreads();
    float m = red2[0], inv = red2[1];
    for (int a = tid; a < 197; a += 256) ev[a] = __expf(ev[a] - m) * inv;
    __syncthreads();

    int d = tid*2;
    const u16* afb = af + (size_t)b*196*512 + d;
    float s0 = 0.f, s1 = 0.f, t0 = 0.f, t1 = 0.f;
    for (int a = 0; a < 196; a += 2){
        float e0 = ev[a+1], e1 = ev[a+2];
        u32 u0 = *(const u32*)(afb + (size_t)a*512);
        u32 u1 = *(const u32*)(afb + (size_t)(a+1)*512);
        s0 += e0 * __uint_as_float(u0 << 16);
        s1 += e0 * __uint_as_float(u0 & 0xFFFF0000u);
        t0 += e1 * __uint_as_float(u1 << 16);
        t1 += e1 * __uint_as_float(u1 & 0xFFFF0000u);
    }
    float e00 = ev[0];
    float a0 = e00*sent_lin_f[(size_t)row*512 + d]     + s0 + t0 + h_lin_f[(size_t)row*512 + d];
    float a1 = e00*sent_lin_f[(size_t)row*512 + d + 1] + s1 + t1 + h_lin_f[(size_t)row*512 + d + 1];
    ctx_in[(size_t)row*512 + d]     = f2b(a0);
    ctx_in[(size_t)row*512 + d + 1] = f2b(a1);
}

// ---------------- row log-softmax over 7800: single global read, row cached in regs ----------------
__global__ __launch_bounds__(256) void logsoftmax_kernel(const u16* __restrict__ logits, void* __restrict__ out,
                                                         const int* __restrict__ dflag){
    __shared__ float red[256];
    bool f32 = (*dflag != 0);
    int row = blockIdx.x, tid = threadIdx.x;
    const u16* lp = logits + (size_t)row*7808;
    float xs[31];
    float m = -1e30f;
    #pragma unroll
    for (int k = 0; k < 31; ++k){
        int v = k*256 + tid;
        xs[k] = (v < 7800) ? b2f(lp[v]) : -1e30f;
        m = fmaxf(m, xs[k]);
    }
    red[tid] = m; __syncthreads();
    for (int s = 128; s; s >>= 1){ if (tid < s) red[tid] = fmaxf(red[tid], red[tid+s]); __syncthreads(); }
    m = red[0]; __syncthreads();
    float s = 0.f;
    #pragma unroll
    for (int k = 0; k < 31; ++k) s += __expf(xs[k] - m);
    red[tid] = s; __syncthreads();
    for (int st = 128; st; st >>= 1){ if (tid < st) red[tid] += red[tid+st]; __syncthreads(); }
    float lse = m + __logf(red[0]);
    if (f32){
        float* op = (float*)out + (size_t)row*7800;
        #pragma unroll
        for (int k = 0; k < 31; ++k){
            int v = k*256 + tid;
            if (v < 7800) op[v] = xs[k] - lse;
        }
    } else {
        u16* op = (u16*)out + (size_t)row*7800;
        #pragma unroll
        for (int k = 0; k < 31; ++k){
            int v = k*256 + tid;
            if (v < 7800) op[v] = f2b(xs[k] - lse);
        }
    }
}

extern "C" void kernel_launch(void* const* d_in, const int* in_sizes, int n_in,
                              void* d_out, int out_size, void* d_ws, size_t ws_size,
                              hipStream_t stream){
    (void)in_sizes; (void)n_in; (void)out_size; (void)ws_size;
    const int* seq    = (const int*)d_in[0];
    const void* att   = d_in[1];
    const void* embed = d_in[2];
    const void* W_word= d_in[3];  const void* b_word = d_in[4];
    const void* W_h   = d_in[5];  const void* b_h    = d_in[6];
    const void* W_img = d_in[7];  const void* b_img  = d_in[8];
    const void* W_ae  = d_in[9];  const void* b_ae   = d_in[10];
    const void* W_c2a = d_in[11]; const void* b_c2a  = d_in[12];
    const void* W_sl  = d_in[13]; const void* b_sl   = d_in[14];
    const void* W_se  = d_in[15]; const void* b_se   = d_in[16];
    const void* W_hl  = d_in[17]; const void* b_hl   = d_in[18];
    const void* W_he  = d_in[19]; const void* b_he   = d_in[20];
    const void* W_al  = d_in[21]; const void* b_al   = d_in[22];
    const void* W_a2h = d_in[23]; const void* b_a2h  = d_in[24];
    const void* W_log = d_in[25]; const void* b_log  = d_in[26];

    char* p = (char*)d_ws;
    auto alloc = [&](size_t bytes)->char*{ char* r = p; p += (bytes + 255) & ~(size_t)255; return r; };

    int* dflag   = (int*)alloc(256);
    u16* WT_ae   = (u16*)alloc((size_t)512*2048*2);
    u16* WT_word = (u16*)alloc((size_t)3072*512*2);
    u16* WT_h    = (u16*)alloc((size_t)3072*512*2);
    u16* WT_img  = (u16*)alloc((size_t)3072*512*2);
    u16* WT_c2a  = (u16*)alloc((size_t)512*512*2);
    u16* WT_sl   = (u16*)alloc((size_t)512*512*2);
    u16* WT_se   = (u16*)alloc((size_t)512*512*2);
    u16* WT_hl   = (u16*)alloc((size_t)512*512*2);
    u16* WT_he   = (u16*)alloc((size_t)512*512*2);
    u16* WT_a2h  = (u16*)alloc((size_t)512*512*2);
    u16* WT_log  = (u16*)alloc((size_t)7808*512*2);
    u16* af      = (u16*)alloc((size_t)12544*512*2);
    u16* p_att   = (u16*)alloc((size_t)12544*512*2);
    u16* meanb   = (u16*)alloc((size_t)64*512*2);
    float* imgg  = (float*)alloc((size_t)64*3072*4);
    u16* xemb    = (u16*)alloc((size_t)1280*512*2);
    float* wgb   = (float*)alloc((size_t)1280*3072*4);   // [t][b][512][6] layout
    u16* hb0     = (u16*)alloc((size_t)64*512*2);
    u16* hb1     = (u16*)alloc((size_t)64*512*2);
    float* cst   = (float*)alloc((size_t)64*512*4);
    u16* sent_all= (u16*)alloc((size_t)1280*512*2);
    u16* hy_all  = (u16*)alloc((size_t)1280*512*2);
    float* slf   = (float*)alloc((size_t)1280*512*4);
    u16* slb     = (u16*)alloc((size_t)1280*512*2);
    float* hlf   = (float*)alloc((size_t)1280*512*4);
    u16* hlb     = (u16*)alloc((size_t)1280*512*2);
    u16* sembb   = (u16*)alloc((size_t)1280*512*2);
    float* hemb  = (float*)alloc((size_t)1280*512*4);
    u16* ctx     = (u16*)alloc((size_t)1280*512*2);
    u16* a2hb    = (u16*)alloc((size_t)1280*512*2);
    float* evg   = (float*)alloc((size_t)1280*256*4);
    u16* logits  = (u16*)alloc((size_t)1280*7808*2);

    // attb (51.4MB) aliases late-lifetime region [wgb .. logits]:
    // written by prep_all, consumed only by af GEMM, dead before wgb is written.
    u16* attb = (u16*)wgb;

    probe_dtype<<<1, 64, 0, stream>>>(W_ae, dflag);

    {
        PREP pp{};
        pp.tsrc[0]=W_c2a; pp.tdst[0]=WT_c2a;
        pp.tsrc[1]=W_sl;  pp.tdst[1]=WT_sl;
        pp.tsrc[2]=W_se;  pp.tdst[2]=WT_se;
        pp.tsrc[3]=W_hl;  pp.tdst[3]=WT_hl;
        pp.tsrc[4]=W_he;  pp.tdst[4]=WT_he;
        pp.tsrc[5]=W_a2h; pp.tdst[5]=WT_a2h;
        pp.tsrc[6]=W_word;pp.tdst[6]=WT_word;
        pp.tsrc[7]=W_h;   pp.tdst[7]=WT_h;
        pp.tsrc[8]=W_img; pp.tdst[8]=WT_img;
        pp.tsrc[9]=W_ae;  pp.tdst[9]=WT_ae;
        pp.tsrc[10]=W_log;pp.tdst[10]=WT_log;
        pp.seq = seq; pp.embed = embed; pp.xemb = xemb;
        pp.att = att; pp.attb = attb;
        prep_all<<<17872, 256, 0, stream>>>(pp, dflag);
    }

    hipMemsetAsync(hb0, 0, (size_t)64*512*2, stream);
    hipMemsetAsync(cst, 0, (size_t)64*512*4, stream);

    // af = relu(att @ W_ae + b_ae)  -- TM=64, 1568 blocks
    gemm_tn<64><<<dim3(8,196), 256, 0, stream>>>(attb, WT_ae, 512, 2048,
                                                 b_ae, nullptr, nullptr, 1, nullptr, af, 1, 512, 12544, dflag, 0);
    // p_att = af @ W_c2a + b_c2a  -- TM=64
    gemm_tn<64><<<dim3(8,196), 256, 0, stream>>>(af, WT_c2a, 512, 512,
                                                 b_c2a, nullptr, nullptr, 1, nullptr, p_att, 0, 512, 12544, dflag, 0);
    mean_af_kernel<<<64, 256, 0, stream>>>(af, meanb);
    gemm_tn<64><<<dim3(48,1), 256, 0, stream>>>(meanb, WT_img, 3072, 512,
                                                b_img, nullptr, nullptr, 1, imgg, nullptr, 0, 3072, 64, dflag, 0);
    // wgb[t][b][r][6] = x_emb @ W_word + b_word + b_h + img_gate[b]   (perm store; overwrites attb region)
    gemm_tn<64><<<dim3(48,20), 256, 0, stream>>>(xemb, WT_word, 3072, 512,
                                                 b_word, b_h, imgg, 20, wgb, nullptr, 0, 3072, 1280, dflag, 1);

    // sequential recurrence, per-step launches; 256 blocks x 192 thr each
    for (int t = 0; t < 20; ++t){
        const u16* hin = (t & 1) ? hb1 : hb0;
        u16* hout      = (t & 1) ? hb0 : hb1;
        lstm_step<<<256, 192, 0, stream>>>(hin, WT_h, wgb, cst, hout, sent_all, hy_all, t);
    }

    // post-recurrence, z-batched pairs
    GP2 pa{};
    pa.g[0] = { sent_all, WT_sl, b_sl, slf, slb, 1 };
    pa.g[1] = { hy_all,   WT_hl, b_hl, hlf, hlb, 2 };
    gemm_tn2<<<dim3(8,20,2), 256, 0, stream>>>(pa, 512, 512, 512, 1280, dflag);
    GP2 pb{};
    pb.g[0] = { slb, WT_se, b_se, nullptr, sembb, 0 };
    pb.g[1] = { hlb, WT_he, b_he, hemb, nullptr, 0 };
    gemm_tn2<<<dim3(8,20,2), 256, 0, stream>>>(pb, 512, 512, 512, 1280, dflag);

    // attention: high-occupancy score pass, then softmax+ctx pass
    attn_score<<<dim3(1280,4), 256, 0, stream>>>(sembb, hemb, p_att, W_al, b_al, evg, dflag);
    attn_ctx<<<1280, 256, 0, stream>>>(evg, slf, hlf, af, ctx);

    gemm_tn<64><<<dim3(8,20), 256, 0, stream>>>(ctx, WT_a2h, 512, 512,
                                                b_a2h, nullptr, nullptr, 1, nullptr, a2hb, 2, 512, 1280, dflag, 0);
    gemm_tn<64><<<dim3(122,20), 256, 0, stream>>>(a2hb, WT_log, 7808, 512,
                                                  b_log, nullptr, nullptr, 1, nullptr, logits, 0, 7800, 1280, dflag, 0);
    logsoftmax_kernel<<<1280, 256, 0, stream>>>(logits, d_out, dflag);
}

// Round 19
// 392.632 us; speedup vs baseline: 1.0784x; 1.0014x over previous
//
#include <hip/hip_runtime.h>

using short8 = __attribute__((ext_vector_type(8))) short;
using f32x4  = __attribute__((ext_vector_type(4))) float;
typedef unsigned short u16;
typedef unsigned int u32;

__device__ __forceinline__ float b2f(u16 u){
    return __uint_as_float(((u32)u) << 16);
}
__device__ __forceinline__ u16 f2b(float f){
    u32 x = __float_as_uint(f);
    u32 r = (x + 0x7FFFu + ((x >> 16) & 1u)) >> 16;
    return (u16)r;
}
__device__ __forceinline__ float ldx(const void* p, size_t i, bool f32){
    return f32 ? ((const float*)p)[i] : b2f(((const u16*)p)[i]);
}
__device__ __forceinline__ float sigf(float x){
    return __builtin_amdgcn_rcpf(1.0f + __expf(-x));
}
__device__ __forceinline__ float tanhf_(float x){
    float e = __expf(2.0f*x);
    return 1.0f - 2.0f*__builtin_amdgcn_rcpf(e + 1.0f);
}

#define GLDS(g, l) __builtin_amdgcn_global_load_lds((const __attribute__((address_space(1))) void*)(g), \
                        (__attribute__((address_space(3))) void*)(l), 16, 0, 0)

// ---------------- dtype probe ----------------
__global__ void probe_dtype(const void* w, int* flag){
    const u16* up = (const u16*)w;
    int lane = threadIdx.x & 63;
    int cnt = 0;
    for (int i = lane; i < 256; i += 64){
        u16 u = up[2*i];
        int e = (u >> 7) & 0xFF;
        if (e >= 100 && e <= 126) cnt++;
    }
    #pragma unroll
    for (int off = 32; off; off >>= 1) cnt += __shfl_xor(cnt, off);
    if (lane == 0) *flag = (cnt >= 192) ? 0 : 1;   // 1 == inputs are f32
}

// ---------------- fused prep v4: 64x64 transposes + gather + chunk-coalesced convert ----------------
// block ranges: [0,384) six 512x512; [384,1536) three 512x3072; [1536,1792) W_ae 2048x512;
// [1792,2768) W_log 512x7800->7808; [2768,5328) gather_emb; [5328,17872) convert_att (2048 elems/block).
struct PREP {
    const void* tsrc[11]; u16* tdst[11];
    const int* seq; const void* embed; u16* xemb;
    const void* att; u16* attb;
};
__global__ __launch_bounds__(256) void prep_all(PREP pp, const int* __restrict__ dflag){
    __shared__ u16 T[64][66];
    bool f32 = (*dflag != 0);
    int blk = blockIdx.x;
    int tid = threadIdx.x;
    if (blk < 2768){
        int z, bx, by, K, N, Npad;
        if (blk < 384){ z = blk >> 6; int idx = blk & 63; bx = idx & 7; by = idx >> 3; K=512; N=512; Npad=512; }
        else if (blk < 1536){ int rel = blk - 384; z = 6 + rel/384; int idx = rel%384; bx = idx%48; by = idx/48; K=512; N=3072; Npad=3072; }
        else if (blk < 1792){ int rel = blk - 1536; z = 9; bx = rel & 7; by = rel >> 3; K=2048; N=512; Npad=512; }
        else { int rel = blk - 1792; z = 10; bx = rel % 122; by = rel / 122; K=512; N=7800; Npad=7808; }
        const void* in = pp.tsrc[z];
        u16* out = pp.tdst[z];
        int tx = tid & 63, ty = tid >> 6;   // (64,4)
        int n = bx*64 + tx;
        #pragma unroll
        for (int i = 0; i < 64; i += 4){
            int k = by*64 + ty + i;
            u16 v = 0;
            if (n < N && k < K)
                v = f32 ? f2b(((const float*)in)[(size_t)k*N + n]) : ((const u16*)in)[(size_t)k*N + n];
            T[tx][ty + i] = v;              // T[n_local][k_local]
        }
        __syncthreads();
        int k2 = by*64 + tx;
        #pragma unroll
        for (int i = 0; i < 64; i += 4){
            int n2 = bx*64 + ty + i;
            if (n2 < Npad && k2 < K) out[(size_t)n2*K + k2] = T[ty + i][tx];
        }
    } else if (blk < 5328){
        int idx = (blk - 2768)*256 + tid;
        if (idx < 1280*512){
            int row = idx >> 9, r = idx & 511;
            int b = row / 20, t = row % 20;
            int w = pp.seq[b*21 + t];
            float v = ldx(pp.embed, (size_t)w*512 + r, f32);
            pp.xemb[idx] = f2b(fmaxf(v, 0.f));
        }
    } else {
        // 2048 elems/block: two fully lane-contiguous load/store pairs
        size_t base = (size_t)(blk - 5328)*2048;
        int t4 = tid*4;
        if (f32){
            const float* A = (const float*)pp.att;
            float4 v0 = *(const float4*)(A + base + t4);
            float4 v1 = *(const float4*)(A + base + 1024 + t4);
            u16 o0[4] = { f2b(v0.x),f2b(v0.y),f2b(v0.z),f2b(v0.w) };
            u16 o1[4] = { f2b(v1.x),f2b(v1.y),f2b(v1.z),f2b(v1.w) };
            *(uint2*)(pp.attb + base + t4)        = *(const uint2*)o0;
            *(uint2*)(pp.attb + base + 1024 + t4) = *(const uint2*)o1;
        } else {
            const u16* A = (const u16*)pp.att;
            *(uint2*)(pp.attb + base + t4)        = *(const uint2*)(A + base + t4);
            *(uint2*)(pp.attb + base + 1024 + t4) = *(const uint2*)(A + base + 1024 + t4);
        }
    }
}

// ---------------- mean over A of af -> bf16 ----------------
__global__ __launch_bounds__(256) void mean_af_kernel(const u16* __restrict__ af, u16* __restrict__ mean_af){
    int b = blockIdx.x, tid = threadIdx.x;
    for (int r = tid; r < 512; r += 256){
        float s = 0.f;
        for (int a = 0; a < 196; ++a) s += b2f(af[((size_t)(b*196+a))*512 + r]);
        mean_af[b*512+r] = f2b(s * (1.0f/196.0f));
    }
}

// ---------------- MFMA GEMM: A(M,K) bf16, BT(Npad,K) bf16; tile TM x 64, BK=64 ----------------
// perm: if 1, C index remapped for wgb: row b*20+t -> t*64+b, col gate*512+r -> r*6+gate
template<int TM>
__global__ __launch_bounds__(256) void gemm_tn(const u16* __restrict__ A, const u16* __restrict__ BT,
                                               int N, int K,
                                               const void* __restrict__ bias1, const void* __restrict__ bias2,
                                               const float* __restrict__ rowAdd, int rowDiv,
                                               float* __restrict__ Cf, u16* __restrict__ Cb,
                                               int act, int Nvalid, int Mvalid,
                                               const int* __restrict__ dflag, int perm){
    constexpr int MW = TM/64;
    __shared__ u16 As[TM*64];
    __shared__ u16 Bs[64*64];
    bool f32 = (*dflag != 0);
    int tid = threadIdx.x, lane = tid & 63, w = tid >> 6;
    int lr = lane & 15, kq = lane >> 4;

    int gN = gridDim.x;
    int nwg = gN * gridDim.y;
    int flat = blockIdx.y*gN + blockIdx.x;
    int q = nwg >> 3, r = nwg & 7;
    int xcd = flat & 7, pos = flat >> 3;
    int wgid = (xcd < r ? xcd*(q+1) : r*(q+1) + (xcd-r)*q) + pos;
    int bm = wgid / gN, bn = wgid % gN;
    int row0 = bm*TM, col0 = bn*64;

    f32x4 acc[MW][4];
    #pragma unroll
    for (int m=0;m<MW;++m)
        #pragma unroll
        for (int n=0;n<4;++n) acc[m][n] = (f32x4){0.f,0.f,0.f,0.f};

    for (int k0 = 0; k0 < K; k0 += 64){
        #pragma unroll
        for (int i=0;i<TM/32;++i){
            int c = i*256 + tid;
            int row = c>>3, slot = (c&7) ^ (row&7);
            GLDS((const char*)A + ((size_t)(row0+row)*K + k0)*2 + slot*16,
                 As + (size_t)(i*256 + w*64)*8);
        }
        #pragma unroll
        for (int i=0;i<2;++i){
            int c = i*256 + tid;
            int row = c>>3, slot = (c&7) ^ (row&7);
            GLDS((const char*)BT + ((size_t)(col0+row)*K + k0)*2 + slot*16,
                 Bs + (size_t)(i*256 + w*64)*8);
        }
        __syncthreads();
        short8 av[MW][2], bv[4][2];
        #pragma unroll
        for (int ks=0;ks<2;++ks){
            #pragma unroll
            for (int m=0;m<MW;++m){
                int rrow = w*(TM/4) + m*16 + lr;
                int sl = (ks*4+kq) ^ (rrow&7);
                av[m][ks] = *(const short8*)(As + rrow*64 + sl*8);
            }
            #pragma unroll
            for (int n=0;n<4;++n){
                int rrow = n*16 + lr;
                int sl = (ks*4+kq) ^ (rrow&7);
                bv[n][ks] = *(const short8*)(Bs + rrow*64 + sl*8);
            }
        }
        #pragma unroll
        for (int ks=0;ks<2;++ks)
            #pragma unroll
            for (int m=0;m<MW;++m)
                #pragma unroll
                for (int n=0;n<4;++n)
                    acc[m][n] = __builtin_amdgcn_mfma_f32_16x16x32_bf16(av[m][ks], bv[n][ks], acc[m][n], 0,0,0);
        __syncthreads();
    }

    #pragma unroll
    for (int n=0;n<4;++n){
        int col = col0 + n*16 + lr;
        float bvv = 0.f;
        if (col < Nvalid){
            if (bias1) bvv += ldx(bias1, col, f32);
            if (bias2) bvv += ldx(bias2, col, f32);
        }
        #pragma unroll
        for (int m=0;m<MW;++m){
            #pragma unroll
            for (int rr=0;rr<4;++rr){
                int row = row0 + w*(TM/4) + m*16 + kq*4 + rr;
                if (row < Mvalid && col < Nvalid){
                    float v = acc[m][n][rr] + bvv;
                    if (rowAdd) v += rowAdd[(size_t)(row/rowDiv)*N + col];
                    if (act == 1) v = fmaxf(v, 0.f);
                    else if (act == 2) v = tanhf_(v);
                    size_t o;
                    if (perm){
                        int orow = (row % 20)*64 + row/20;
                        int ocol = (col & 511)*6 + (col >> 9);
                        o = (size_t)orow*N + ocol;
                    } else {
                        o = (size_t)row*N + col;
                    }
                    if (Cf) Cf[o] = v;
                    if (Cb) Cb[o] = f2b(v);
                }
            }
        }
    }
}

// ---------------- z-batched pair of 512x512 GEMMs (M=1280), TM=64 ----------------
struct GP { const u16* A; const u16* BT; const void* b1; float* Cf; u16* Cb; int act; };
struct GP2 { GP g[2]; };
__global__ __launch_bounds__(256) void gemm_tn2(GP2 ps, int N, int K, int Nvalid, int Mvalid,
                                                const int* __restrict__ dflag){
    __shared__ u16 As[64*64];
    __shared__ u16 Bs[64*64];
    bool f32 = (*dflag != 0);
    GP gp = ps.g[blockIdx.z];
    int tid = threadIdx.x, lane = tid & 63, w = tid >> 6;
    int lr = lane & 15, kq = lane >> 4;

    int gN = gridDim.x;
    int nwg = gN * gridDim.y;
    int flat = blockIdx.y*gN + blockIdx.x;
    int q = nwg >> 3, r = nwg & 7;
    int xcd = flat & 7, pos = flat >> 3;
    int wgid = (xcd < r ? xcd*(q+1) : r*(q+1) + (xcd-r)*q) + pos;
    int bm = wgid / gN, bn = wgid % gN;
    int row0 = bm*64, col0 = bn*64;

    f32x4 acc[4];
    #pragma unroll
    for (int n=0;n<4;++n) acc[n] = (f32x4){0.f,0.f,0.f,0.f};

    for (int k0 = 0; k0 < K; k0 += 64){
        {
            int c = tid;
            int row = c>>3, slot = (c&7) ^ (row&7);
            GLDS((const char*)gp.A + ((size_t)(row0+row)*K + k0)*2 + slot*16,
                 As + (size_t)(w*64)*8);
            c = 256 + tid;
            row = c>>3; slot = (c&7) ^ (row&7);
            GLDS((const char*)gp.A + ((size_t)(row0+row)*K + k0)*2 + slot*16,
                 As + (size_t)(256 + w*64)*8);
            c = tid;
            row = c>>3; slot = (c&7) ^ (row&7);
            GLDS((const char*)gp.BT + ((size_t)(col0+row)*K + k0)*2 + slot*16,
                 Bs + (size_t)(w*64)*8);
            c = 256 + tid;
            row = c>>3; slot = (c&7) ^ (row&7);
            GLDS((const char*)gp.BT + ((size_t)(col0+row)*K + k0)*2 + slot*16,
                 Bs + (size_t)(256 + w*64)*8);
        }
        __syncthreads();
        short8 av[2], bv[4][2];
        #pragma unroll
        for (int ks=0;ks<2;++ks){
            int rrow = w*16 + lr;
            int sl = (ks*4+kq) ^ (rrow&7);
            av[ks] = *(const short8*)(As + rrow*64 + sl*8);
            #pragma unroll
            for (int n=0;n<4;++n){
                int rr2 = n*16 + lr;
                int sl2 = (ks*4+kq) ^ (rr2&7);
                bv[n][ks] = *(const short8*)(Bs + rr2*64 + sl2*8);
            }
        }
        #pragma unroll
        for (int ks=0;ks<2;++ks)
            #pragma unroll
            for (int n=0;n<4;++n)
                acc[n] = __builtin_amdgcn_mfma_f32_16x16x32_bf16(av[ks], bv[n][ks], acc[n], 0,0,0);
        __syncthreads();
    }

    #pragma unroll
    for (int n=0;n<4;++n){
        int col = col0 + n*16 + lr;
        float bvv = (col < Nvalid && gp.b1) ? ldx(gp.b1, col, f32) : 0.f;
        #pragma unroll
        for (int rr=0;rr<4;++rr){
            int row = row0 + w*16 + kq*4 + rr;
            if (row < Mvalid && col < Nvalid){
                float v = acc[n][rr] + bvv;
                if (gp.act == 1) v = fmaxf(v, 0.f);
                else if (gp.act == 2) v = tanhf_(v);
                size_t o = (size_t)row*N + col;
                if (gp.Cf) gp.Cf[o] = v;
                if (gp.Cb) gp.Cb[o] = f2b(v);
            }
        }
    }
}

// ---------------- LSTM step v3: 256 blocks x 192 thr; wgb in [t][b][r][6] layout ----------------
#define GP3 52
__global__ __launch_bounds__(192) void lstm_step(const u16* __restrict__ h_in, const u16* __restrict__ WT_h,
                                                 const float* __restrict__ wgb, float* __restrict__ cstate,
                                                 u16* __restrict__ h_out, u16* __restrict__ sent_all,
                                                 u16* __restrict__ hy_all, int t){
    __shared__ float gates[16*GP3];
    int tid = threadIdx.x, lane = tid & 63, w = tid >> 6;   // w in 0..2
    int mg = blockIdx.x >> 6, rg = blockIdx.x & 63;
    int b0 = mg*16, r0 = rg*8;
    int lr = lane & 15, kq = lane >> 4, kg = kq*8;
    int c = w*16 + lr;                    // block col 0..47 = gate*8 + (r-r0)
    int gate = c >> 3, rcol = r0 + (c & 7);
    const u16* Ap = h_in + (size_t)(b0 + lr)*512 + kg;
    const u16* Bp = WT_h + ((size_t)gate*512 + rcol)*512 + kg;
    f32x4 acc = (f32x4){0.f,0.f,0.f,0.f};
    #pragma unroll
    for (int k0 = 0; k0 < 512; k0 += 32){
        short8 a  = *(const short8*)(Ap + k0);
        short8 bf = *(const short8*)(Bp + k0);
        acc = __builtin_amdgcn_mfma_f32_16x16x32_bf16(a, bf, acc, 0,0,0);
    }
    #pragma unroll
    for (int rr = 0; rr < 4; ++rr)
        gates[(kq*4+rr)*GP3 + c] = acc[rr];
    __syncthreads();
    if (tid < 128){
        int ri = tid >> 3, rr = tid & 7;
        int b = b0 + ri, r = r0 + rr;
        const float* wp = wgb + (((size_t)t*64 + b)*512 + r)*6;
        float2 w01 = *(const float2*)(wp);
        float2 w23 = *(const float2*)(wp + 2);
        float2 w45 = *(const float2*)(wp + 4);
        float g0 = gates[ri*GP3 +      rr] + w01.x;
        float g1 = gates[ri*GP3 +  8 + rr] + w01.y;
        float g2 = gates[ri*GP3 + 16 + rr] + w23.x;
        float g3 = gates[ri*GP3 + 24 + rr] + w23.y;
        float g4 = gates[ri*GP3 + 32 + rr] + w45.x;
        float g5 = gates[ri*GP3 + 40 + rr] + w45.y;
        float ig = sigf(g0), fg = sigf(g1), og = sigf(g2), sg = sigf(g3);
        float cell = fmaxf(g4, g5);
        float co = cstate[b*512 + r];
        float cy = tanhf_(fg*co + ig*cell);
        cstate[b*512 + r] = cy;
        float sent = sg*cy, hy = og*cy;
        h_out[(size_t)b*512 + r] = f2b(hy);
        size_t rgl = (size_t)b*20 + t;
        sent_all[rgl*512 + r] = f2b(sent);
        hy_all[rgl*512 + r]   = f2b(hy);
    }
}

// ---------------- attention scores: grid (1280, 4); chunk c handles a ≡ c (mod 4) ----------------
__global__ __launch_bounds__(256) void attn_score(const u16* __restrict__ sembb, const float* __restrict__ h_emb,
                                                  const u16* __restrict__ p_att,
                                                  const void* __restrict__ W_al, const void* __restrict__ b_al,
                                                  float* __restrict__ evg, const int* __restrict__ dflag){
    __shared__ float he_s[512];
    __shared__ float wal_s[512];
    bool f32 = (*dflag != 0);
    int flat = blockIdx.x;
    int row = (flat & 7)*160 + (flat >> 3);   // XCD-clustered rows (1280 = 8*160)
    int b = row / 20;
    int chunk = blockIdx.y;
    int tid = threadIdx.x, lane = tid & 63, w = tid >> 6;
    for (int d = tid; d < 512; d += 256){
        int ad = ((d & 7) >> 1)*128 + (d >> 3)*2 + (d & 1);
        he_s[ad]  = h_emb[(size_t)row*512 + d];
        wal_s[ad] = ldx(W_al, d, f32);
    }
    __syncthreads();
    float bal = ldx(b_al, 0, f32);
    float* evr = evg + (size_t)row*256;

    for (int j = w; chunk + 4*j < 197; j += 8){
        int a0i = chunk + 4*j;
        int a1i = a0i + 16;
        bool has2 = (a1i < 197);
        const u16* r0 = (a0i == 0) ? (sembb + (size_t)row*512)
                                   : (p_att + ((size_t)(b*196 + a0i-1))*512);
        const u16* r1 = has2 ? (p_att + ((size_t)(b*196 + a1i-1))*512) : r0;
        short8 v0 = *(const short8*)(r0 + lane*8);
        short8 v1 = *(const short8*)(r1 + lane*8);
        const u32* pk0 = (const u32*)&v0;
        const u32* pk1 = (const u32*)&v1;
        float p0 = 0.f, p1 = 0.f;
        #pragma unroll
        for (int jp = 0; jp < 4; ++jp){
            float2 he2 = *(const float2*)&he_s[jp*128 + lane*2];
            float2 wa2 = *(const float2*)&wal_s[jp*128 + lane*2];
            u32 u0 = pk0[jp], u1 = pk1[jp];
            float x00 = __uint_as_float(u0 << 16)          + he2.x;
            float x01 = __uint_as_float(u0 & 0xFFFF0000u)  + he2.y;
            float x10 = __uint_as_float(u1 << 16)          + he2.x;
            float x11 = __uint_as_float(u1 & 0xFFFF0000u)  + he2.y;
            p0 += tanhf_(x00)*wa2.x;
            p0 += tanhf_(x01)*wa2.y;
            p1 += tanhf_(x10)*wa2.x;
            p1 += tanhf_(x11)*wa2.y;
        }
        #pragma unroll
        for (int off = 32; off; off >>= 1){
            p0 += __shfl_xor(p0, off);
            p1 += __shfl_xor(p1, off);
        }
        if (lane == 0){
            evr[a0i] = p0 + bal;
            if (has2) evr[a1i] = p1 + bal;
        }
    }
}

// ---------------- attention ctx: softmax over 197 + cHat + h_lin -> ctx ----------------
__global__ __launch_bounds__(256) void attn_ctx(const float* __restrict__ evg,
                                                const float* __restrict__ sent_lin_f, const float* __restrict__ h_lin_f,
                                                const u16* __restrict__ af,
                                                u16* __restrict__ ctx_in){
    __shared__ float ev[208];
    __shared__ float red2[2];
    int flat = blockIdx.x;
    int row = (flat & 7)*160 + (flat >> 3);
    int b = row / 20;
    int tid = threadIdx.x, lane = tid & 63, w = tid >> 6;
    const float* evr = evg + (size_t)row*256;
    for (int a = tid; a < 197; a += 256) ev[a] = evr[a];
    __syncthreads();
    if (w == 0){
        float m = -1e30f;
        for (int a = lane; a < 197; a += 64) m = fmaxf(m, ev[a]);
        #pragma unroll
        for (int off = 32; off; off >>= 1) m = fmaxf(m, __shfl_xor(m, off));
        float s = 0.f;
        for (int a = lane; a < 197; a += 64) s += __expf(ev[a] - m);
        #pragma unroll
        for (int off = 32; off; off >>= 1) s += __shfl_xor(s, off);
        if (lane == 0){ red2[0] = m; red2[1] = __builtin_amdgcn_rcpf(s); }
    }
    __syncthreads();
    float m = red2[0], inv = red2[1];
    for (int a = tid; a < 197; a += 256) ev[a] = __expf(ev[a] - m) * inv;
    __syncthreads();

    int d = tid*2;
    const u16* afb = af + (size_t)b*196*512 + d;
    float s0 = 0.f, s1 = 0.f, t0 = 0.f, t1 = 0.f;
    for (int a = 0; a < 196; a += 2){
        float e0 = ev[a+1], e1 = ev[a+2];
        u32 u0 = *(const u32*)(afb + (size_t)a*512);
        u32 u1 = *(const u32*)(afb + (size_t)(a+1)*512);
        s0 += e0 * __uint_as_float(u0 << 16);
        s1 += e0 * __uint_as_float(u0 & 0xFFFF0000u);
        t0 += e1 * __uint_as_float(u1 << 16);
        t1 += e1 * __uint_as_float(u1 & 0xFFFF0000u);
    }
    float e00 = ev[0];
    float a0 = e00*sent_lin_f[(size_t)row*512 + d]     + s0 + t0 + h_lin_f[(size_t)row*512 + d];
    float a1 = e00*sent_lin_f[(size_t)row*512 + d + 1] + s1 + t1 + h_lin_f[(size_t)row*512 + d + 1];
    ctx_in[(size_t)row*512 + d]     = f2b(a0);
    ctx_in[(size_t)row*512 + d + 1] = f2b(a1);
}

// ---------------- row log-softmax over 7800: single global read, row cached in regs ----------------
__global__ __launch_bounds__(256) void logsoftmax_kernel(const u16* __restrict__ logits, void* __restrict__ out,
                                                         const int* __restrict__ dflag){
    __shared__ float red[256];
    bool f32 = (*dflag != 0);
    int row = blockIdx.x, tid = threadIdx.x;
    const u16* lp = logits + (size_t)row*7808;
    float xs[31];
    float m = -1e30f;
    #pragma unroll
    for (int k = 0; k < 31; ++k){
        int v = k*256 + tid;
        xs[k] = (v < 7800) ? b2f(lp[v]) : -1e30f;
        m = fmaxf(m, xs[k]);
    }
    red[tid] = m; __syncthreads();
    for (int s = 128; s; s >>= 1){ if (tid < s) red[tid] = fmaxf(red[tid], red[tid+s]); __syncthreads(); }
    m = red[0]; __syncthreads();
    float s = 0.f;
    #pragma unroll
    for (int k = 0; k < 31; ++k) s += __expf(xs[k] - m);
    red[tid] = s; __syncthreads();
    for (int st = 128; st; st >>= 1){ if (tid < st) red[tid] += red[tid+st]; __syncthreads(); }
    float lse = m + __logf(red[0]);
    if (f32){
        float* op = (float*)out + (size_t)row*7800;
        #pragma unroll
        for (int k = 0; k < 31; ++k){
            int v = k*256 + tid;
            if (v < 7800) op[v] = xs[k] - lse;
        }
    } else {
        u16* op = (u16*)out + (size_t)row*7800;
        #pragma unroll
        for (int k = 0; k < 31; ++k){
            int v = k*256 + tid;
            if (v < 7800) op[v] = f2b(xs[k] - lse);
        }
    }
}

extern "C" void kernel_launch(void* const* d_in, const int* in_sizes, int n_in,
                              void* d_out, int out_size, void* d_ws, size_t ws_size,
                              hipStream_t stream){
    (void)in_sizes; (void)n_in; (void)out_size; (void)ws_size;
    const int* seq    = (const int*)d_in[0];
    const void* att   = d_in[1];
    const void* embed = d_in[2];
    const void* W_word= d_in[3];  const void* b_word = d_in[4];
    const void* W_h   = d_in[5];  const void* b_h    = d_in[6];
    const void* W_img = d_in[7];  const void* b_img  = d_in[8];
    const void* W_ae  = d_in[9];  const void* b_ae   = d_in[10];
    const void* W_c2a = d_in[11]; const void* b_c2a  = d_in[12];
    const void* W_sl  = d_in[13]; const void* b_sl   = d_in[14];
    const void* W_se  = d_in[15]; const void* b_se   = d_in[16];
    const void* W_hl  = d_in[17]; const void* b_hl   = d_in[18];
    const void* W_he  = d_in[19]; const void* b_he   = d_in[20];
    const void* W_al  = d_in[21]; const void* b_al   = d_in[22];
    const void* W_a2h = d_in[23]; const void* b_a2h  = d_in[24];
    const void* W_log = d_in[25]; const void* b_log  = d_in[26];

    char* p = (char*)d_ws;
    auto alloc = [&](size_t bytes)->char*{ char* r = p; p += (bytes + 255) & ~(size_t)255; return r; };

    int* dflag   = (int*)alloc(256);
    u16* WT_ae   = (u16*)alloc((size_t)512*2048*2);
    u16* WT_word = (u16*)alloc((size_t)3072*512*2);
    u16* WT_h    = (u16*)alloc((size_t)3072*512*2);
    u16* WT_img  = (u16*)alloc((size_t)3072*512*2);
    u16* WT_c2a  = (u16*)alloc((size_t)512*512*2);
    u16* WT_sl   = (u16*)alloc((size_t)512*512*2);
    u16* WT_se   = (u16*)alloc((size_t)512*512*2);
    u16* WT_hl   = (u16*)alloc((size_t)512*512*2);
    u16* WT_he   = (u16*)alloc((size_t)512*512*2);
    u16* WT_a2h  = (u16*)alloc((size_t)512*512*2);
    u16* WT_log  = (u16*)alloc((size_t)7808*512*2);
    u16* af      = (u16*)alloc((size_t)12544*512*2);
    u16* p_att   = (u16*)alloc((size_t)12544*512*2);
    u16* meanb   = (u16*)alloc((size_t)64*512*2);
    float* imgg  = (float*)alloc((size_t)64*3072*4);
    u16* xemb    = (u16*)alloc((size_t)1280*512*2);
    float* wgb   = (float*)alloc((size_t)1280*3072*4);   // [t][b][512][6] layout
    u16* hb0     = (u16*)alloc((size_t)64*512*2);
    u16* hb1     = (u16*)alloc((size_t)64*512*2);
    float* cst   = (float*)alloc((size_t)64*512*4);
    u16* sent_all= (u16*)alloc((size_t)1280*512*2);
    u16* hy_all  = (u16*)alloc((size_t)1280*512*2);
    float* slf   = (float*)alloc((size_t)1280*512*4);
    u16* slb     = (u16*)alloc((size_t)1280*512*2);
    float* hlf   = (float*)alloc((size_t)1280*512*4);
    u16* hlb     = (u16*)alloc((size_t)1280*512*2);
    u16* sembb   = (u16*)alloc((size_t)1280*512*2);
    float* hemb  = (float*)alloc((size_t)1280*512*4);
    u16* ctx     = (u16*)alloc((size_t)1280*512*2);
    u16* a2hb    = (u16*)alloc((size_t)1280*512*2);
    float* evg   = (float*)alloc((size_t)1280*256*4);
    u16* logits  = (u16*)alloc((size_t)1280*7808*2);

    // attb (51.4MB) aliases late-lifetime region [wgb .. logits]:
    // written by prep_all, consumed only by af GEMM, dead before wgb is written.
    u16* attb = (u16*)wgb;

    probe_dtype<<<1, 64, 0, stream>>>(W_ae, dflag);

    {
        PREP pp{};
        pp.tsrc[0]=W_c2a; pp.tdst[0]=WT_c2a;
        pp.tsrc[1]=W_sl;  pp.tdst[1]=WT_sl;
        pp.tsrc[2]=W_se;  pp.tdst[2]=WT_se;
        pp.tsrc[3]=W_hl;  pp.tdst[3]=WT_hl;
        pp.tsrc[4]=W_he;  pp.tdst[4]=WT_he;
        pp.tsrc[5]=W_a2h; pp.tdst[5]=WT_a2h;
        pp.tsrc[6]=W_word;pp.tdst[6]=WT_word;
        pp.tsrc[7]=W_h;   pp.tdst[7]=WT_h;
        pp.tsrc[8]=W_img; pp.tdst[8]=WT_img;
        pp.tsrc[9]=W_ae;  pp.tdst[9]=WT_ae;
        pp.tsrc[10]=W_log;pp.tdst[10]=WT_log;
        pp.seq = seq; pp.embed = embed; pp.xemb = xemb;
        pp.att = att; pp.attb = attb;
        prep_all<<<17872, 256, 0, stream>>>(pp, dflag);
    }

    hipMemsetAsync(hb0, 0, (size_t)64*512*2, stream);
    hipMemsetAsync(cst, 0, (size_t)64*512*4, stream);

    // af = relu(att @ W_ae + b_ae)  -- TM=64, 1568 blocks
    gemm_tn<64><<<dim3(8,196), 256, 0, stream>>>(attb, WT_ae, 512, 2048,
                                                 b_ae, nullptr, nullptr, 1, nullptr, af, 1, 512, 12544, dflag, 0);
    // p_att = af @ W_c2a + b_c2a  -- TM=64
    gemm_tn<64><<<dim3(8,196), 256, 0, stream>>>(af, WT_c2a, 512, 512,
                                                 b_c2a, nullptr, nullptr, 1, nullptr, p_att, 0, 512, 12544, dflag, 0);
    mean_af_kernel<<<64, 256, 0, stream>>>(af, meanb);
    gemm_tn<64><<<dim3(48,1), 256, 0, stream>>>(meanb, WT_img, 3072, 512,
                                                b_img, nullptr, nullptr, 1, imgg, nullptr, 0, 3072, 64, dflag, 0);
    // wgb[t][b][r][6] = x_emb @ W_word + b_word + b_h + img_gate[b]   (perm store; overwrites attb region)
    gemm_tn<64><<<dim3(48,20), 256, 0, stream>>>(xemb, WT_word, 3072, 512,
                                                 b_word, b_h, imgg, 20, wgb, nullptr, 0, 3072, 1280, dflag, 1);

    // sequential recurrence, per-step launches; 256 blocks x 192 thr each
    for (int t = 0; t < 20; ++t){
        const u16* hin = (t & 1) ? hb1 : hb0;
        u16* hout      = (t & 1) ? hb0 : hb1;
        lstm_step<<<256, 192, 0, stream>>>(hin, WT_h, wgb, cst, hout, sent_all, hy_all, t);
    }

    // post-recurrence, z-batched pairs
    GP2 pa{};
    pa.g[0] = { sent_all, WT_sl, b_sl, slf, slb, 1 };
    pa.g[1] = { hy_all,   WT_hl, b_hl, hlf, hlb, 2 };
    gemm_tn2<<<dim3(8,20,2), 256, 0, stream>>>(pa, 512, 512, 512, 1280, dflag);
    GP2 pb{};
    pb.g[0] = { slb, WT_se, b_se, nullptr, sembb, 0 };
    pb.g[1] = { hlb, WT_he, b_he, hemb, nullptr, 0 };
    gemm_tn2<<<dim3(8,20,2), 256, 0, stream>>>(pb, 512, 512, 512, 1280, dflag);

    // attention: high-occupancy score pass, then softmax+ctx pass
    attn_score<<<dim3(1280,4), 256, 0, stream>>>(sembb, hemb, p_att, W_al, b_al, evg, dflag);
    attn_ctx<<<1280, 256, 0, stream>>>(evg, slf, hlf, af, ctx);

    gemm_tn<64><<<dim3(8,20), 256, 0, stream>>>(ctx, WT_a2h, 512, 512,
                                                b_a2h, nullptr, nullptr, 1, nullptr, a2hb, 2, 512, 1280, dflag, 0);
    gemm_tn<64><<<dim3(122,20), 256, 0, stream>>>(a2hb, WT_log, 7808, 512,
                                                  b_log, nullptr, nullptr, 1, nullptr, logits, 0, 7800, 1280, dflag, 0);
    logsoftmax_kernel<<<1280, 256, 0, stream>>>(logits, d_out, dflag);
}